// Round 5
// baseline (987.903 us; speedup 1.0000x reference)
//
#include <hip/hip_runtime.h>

__device__ __forceinline__ float silu_f(float x) { return x / (1.f + __expf(-x)); }

__device__ __forceinline__ void atomicMaxF(float* addr, float val) {
    if (val >= 0.f) atomicMax((int*)addr, __float_as_int(val));
    else            atomicMin((unsigned int*)addr, __float_as_uint(val));
}

__global__ void fill_i(int* __restrict__ p, int v, int n) {
    int i = blockIdx.x * blockDim.x + threadIdx.x;
    if (i < n) p[i] = v;
}

__global__ void init_csc(float* __restrict__ csc) {
    if (threadIdx.x == 0) { csc[0] = -3.4e38f; csc[1] = 0.f; }
}

__global__ void hist_kernel(const int* __restrict__ tgt, int* __restrict__ count, int E) {
    int e = blockIdx.x * blockDim.x + threadIdx.x;
    if (e < E) atomicAdd(&count[tgt[e]], 1);
}

// single-block exclusive scan: count[0..n) -> rowptr[0..n], cursor[0..n)
__global__ __launch_bounds__(1024) void scan_kernel(const int* __restrict__ count,
                                                    int* __restrict__ rowptr,
                                                    int* __restrict__ cursor, int n) {
    __shared__ int part[1024];
    int t = threadIdx.x;
    int chunk = (n + 1023) >> 10;
    int beg = t * chunk, end = min(beg + chunk, n);
    int s = 0;
    for (int i = beg; i < end; ++i) s += count[i];
    part[t] = s; __syncthreads();
    for (int off = 1; off < 1024; off <<= 1) {
        int v = (t >= off) ? part[t - off] : 0;
        __syncthreads();
        part[t] += v;
        __syncthreads();
    }
    int run = (t == 0) ? 0 : part[t - 1];
    for (int i = beg; i < end; ++i) { int c = count[i]; rowptr[i] = run; cursor[i] = run; run += c; }
    if (end == n) rowptr[n] = run;
}

// GAT pre-pass: scatter (src, dist) into CSR slot of tgt
__global__ __launch_bounds__(256) void gat_pre_kernel(const int* __restrict__ src,
        const int* __restrict__ tgt, const float* __restrict__ pos,
        int* __restrict__ cursor, int2* __restrict__ sd, int E) {
    int e = blockIdx.x * blockDim.x + threadIdx.x;
    if (e >= E) return;
    int si = src[e], ti = tgt[e];
    float dx = pos[si * 3 + 0] - pos[ti * 3 + 0];
    float dy = pos[si * 3 + 1] - pos[ti * 3 + 1];
    float dz = pos[si * 3 + 2] - pos[ti * 3 + 2];
    float dist = sqrtf(dx * dx + dy * dy + dz * dz);
    int p = atomicAdd(&cursor[ti], 1);
    sd[p] = make_int2(si, __float_as_int(dist));
}

__global__ __launch_bounds__(256) void cross_pre_kernel(const int* __restrict__ csrc,
        const int* __restrict__ ctgt, int* __restrict__ cursor, int* __restrict__ csrc_s, int E) {
    int e = blockIdx.x * blockDim.x + threadIdx.x;
    if (e >= E) return;
    int p = atomicAdd(&cursor[ctgt[e]], 1);
    csrc_s[p] = csrc[e];
}

// Precompute T[i][h] = sum_g exp(-1.125*(d_i - (2/3)g)^2) * We[g][h], d_i = i/64, i in [0,1024].
// grid: 2050 blocks of 96 (first 1025 -> T_L with We_L, rest -> T_P with We_P)
__global__ __launch_bounds__(96) void rbf_table_kernel(const float* __restrict__ We_L,
        const float* __restrict__ We_P, float* __restrict__ T_L, float* __restrict__ T_P) {
    int b = blockIdx.x;
    const float* We = (b < 1025) ? We_L : We_P;
    float* T = (b < 1025) ? T_L : T_P;
    int i = (b < 1025) ? b : b - 1025;
    int h = threadIdx.x;
    float d = (float)i * 0.015625f;  // 1/64
    float acc = 0.f;
#pragma unroll
    for (int g = 0; g < 16; ++g) {
        float t = d - 0.66666667f * (float)g;
        acc += __expf(-1.125f * t * t) * We[g * 96 + h];
    }
    T[i * 96 + h] = acc;
}

// Fused GATv2 v2: wave per node; 3-phase per <=128-edge chunk:
//  P1: per-edge logit via table lerp (+6-shfl dot reduce) -> LDS
//  P2: lane-parallel chunk max + exp-sum (online rescale across chunks)
//  P3: independent-iteration weighted aggregate of xl[src]
__global__ __launch_bounds__(256) void gat_v2_kernel(const int* __restrict__ rowptr,
        const int2* __restrict__ sd, const float* __restrict__ xl, const float* __restrict__ xr,
        const float* __restrict__ T, const float* __restrict__ att,
        const float* __restrict__ bias, float* __restrict__ s, int N) {
    __shared__ float lg[4][128];
    int lane = threadIdx.x & 63;
    int w = threadIdx.x >> 6;
    int n = blockIdx.x * 4 + w;
    if (n >= N) return;
    int h0 = lane, h1 = 64 + lane;
    bool has1 = lane < 32;
    float att0 = att[h0], att1 = has1 ? att[h1] : 0.f;
    float xr0 = xr[(size_t)n * 96 + h0];
    float xr1 = has1 ? xr[(size_t)n * 96 + h1] : 0.f;
    int beg = rowptr[n], end = rowptr[n + 1];
    float m = -3.4e38f, d = 0.f, a0 = 0.f, a1 = 0.f;
    for (int c0 = beg; c0 < end; c0 += 128) {
        int cn = min(128, end - c0);
        // ---- phase 1: logits -> LDS
        for (int jj = 0; jj < cn; ++jj) {
            int2 e = sd[c0 + jj];
            int si = e.x;
            float dist = __int_as_float(e.y);
            float dt = fminf(dist * 64.f, 1023.0f);
            int i = (int)dt;
            float f = dt - (float)i;
            const float* Tr = T + (size_t)i * 96;
            float t0 = Tr[h0], t1 = Tr[96 + h0];
            float ve0 = t0 + f * (t1 - t0);
            float ve1 = 0.f;
            if (has1) {
                float u0 = Tr[h1], u1 = Tr[96 + h1];
                ve1 = u0 + f * (u1 - u0);
            }
            float xl0 = xl[(size_t)si * 96 + h0];
            float xl1 = has1 ? xl[(size_t)si * 96 + h1] : 0.f;
            float v0 = xl0 + xr0 + ve0;
            float v1 = xl1 + xr1 + ve1;
            v0 = fmaxf(v0, 0.f) + 0.2f * fminf(v0, 0.f);
            v1 = fmaxf(v1, 0.f) + 0.2f * fminf(v1, 0.f);
            float t = v0 * att0 + v1 * att1;
#pragma unroll
            for (int off = 1; off < 64; off <<= 1) t += __shfl_xor(t, off, 64);
            if (lane == 0) lg[w][jj] = t;
        }
        // ---- phase 2: chunk max, rescale, weights + sum
        float cm = -3.4e38f;
        for (int base = lane; base < cn; base += 64) cm = fmaxf(cm, lg[w][base]);
#pragma unroll
        for (int off = 1; off < 64; off <<= 1) cm = fmaxf(cm, __shfl_xor(cm, off, 64));
        float nm = fmaxf(m, cm);
        float sc = __expf(m - nm);
        d *= sc; a0 *= sc; a1 *= sc;
        float cs = 0.f;
        for (int base = lane; base < cn; base += 64) {
            float wv = __expf(lg[w][base] - nm);
            lg[w][base] = wv;
            cs += wv;
        }
#pragma unroll
        for (int off = 1; off < 64; off <<= 1) cs += __shfl_xor(cs, off, 64);
        d += cs;
        m = nm;
        // ---- phase 3: weighted aggregate (independent iterations)
        for (int jj = 0; jj < cn; ++jj) {
            int si = sd[c0 + jj].x;
            float wv = lg[w][jj];
            a0 += wv * xl[(size_t)si * 96 + h0];
            if (has1) a1 += wv * xl[(size_t)si * 96 + h1];
        }
    }
    float agg0 = (d > 0.f) ? a0 / d : 0.f;
    float agg1 = (d > 0.f) ? a1 / d : 0.f;
    s[(size_t)n * 96 + h0] += silu_f(agg0 + bias[h0]);
    if (has1) s[(size_t)n * 96 + h1] += silu_f(agg1 + bias[h1]);
}

// cross logits node-major: q in registers, gather k rows once; write logit to CSR slot
__global__ __launch_bounds__(256) void cross_logit_node_kernel(const int* __restrict__ rowptr,
        const int* __restrict__ csrc_s, const float* __restrict__ qn, const float* __restrict__ kn,
        float* __restrict__ clog_s, float* __restrict__ csc, int N) {
    int lane = threadIdx.x & 63;
    int n = blockIdx.x * 4 + (threadIdx.x >> 6);
    if (n >= N) return;
    int h0 = lane, h1 = 64 + lane;
    bool has1 = lane < 32;
    float q0 = qn[(size_t)n * 96 + h0];
    float q1 = has1 ? qn[(size_t)n * 96 + h1] : 0.f;
    int beg = rowptr[n], end = rowptr[n + 1];
    float mx = -3.4e38f;
    for (int j = beg; j < end; ++j) {
        int si = csrc_s[j];
        float t = q0 * kn[(size_t)si * 96 + h0];
        if (has1) t += q1 * kn[(size_t)si * 96 + h1];
#pragma unroll
        for (int off = 1; off < 64; off <<= 1) t += __shfl_xor(t, off, 64);
        t *= 0.125f;
        if (lane == 0) clog_s[j] = t;
        mx = fmaxf(mx, t);
    }
    if (lane == 0 && end > beg) atomicMaxF(&csc[0], mx);
}

__global__ __launch_bounds__(256) void cross_denom_kernel(const float* __restrict__ clog_s,
                                                          float* __restrict__ csc, int E) {
    int e = blockIdx.x * blockDim.x + threadIdx.x;
    float a = 0.f;
    float mg = csc[0];
    if (e < E) a = __expf(clog_s[e] - mg);
    __shared__ float red[256];
    red[threadIdx.x] = a; __syncthreads();
    for (int s = 128; s > 0; s >>= 1) {
        if (threadIdx.x < s) red[threadIdx.x] += red[threadIdx.x + s];
        __syncthreads();
    }
    if (threadIdx.x == 0) atomicAdd(&csc[1], red[0]);
}

__global__ __launch_bounds__(256) void cross_apply_node_kernel(const int* __restrict__ rowptr,
        const int* __restrict__ csrc_s, const float* __restrict__ clog_s,
        const float* __restrict__ vn, const float* __restrict__ csc,
        float* __restrict__ sL, int N) {
    int lane = threadIdx.x & 63;
    int n = blockIdx.x * 4 + (threadIdx.x >> 6);
    if (n >= N) return;
    int h0 = lane, h1 = 64 + lane;
    bool has1 = lane < 32;
    int beg = rowptr[n], end = rowptr[n + 1];
    if (beg == end) return;
    float M = csc[0], invD = 1.f / csc[1];
    float a0 = 0.f, a1 = 0.f;
    for (int j = beg; j < end; ++j) {
        int si = csrc_s[j];
        float w = __expf(clog_s[j] - M);
        a0 += w * vn[(size_t)si * 96 + h0];
        if (has1) a1 += w * vn[(size_t)si * 96 + h1];
    }
    sL[(size_t)n * 96 + h0] += a0 * invD;
    if (has1) sL[(size_t)n * 96 + h1] += a1 * invD;
}

// ---------- row-blocked dense kernels ----------

__global__ __launch_bounds__(192) void embed2_kernel(const float* __restrict__ x,
        const float* __restrict__ W, const float* __restrict__ b,
        float* __restrict__ s, int N, int D) {
    __shared__ float xs[16 * 167];
    int t = threadIdx.x, half = t / 96, h = t - half * 96;
    int n0 = blockIdx.x * 16;
    for (int i = t; i < 16 * D; i += 192) {
        int r = i / D, dd = i - r * D, nn = n0 + r;
        xs[i] = (nn < N) ? x[(size_t)nn * D + dd] : 0.f;
    }
    __syncthreads();
    float acc[8]; float bb = b[h];
#pragma unroll
    for (int r = 0; r < 8; ++r) acc[r] = bb;
    const float* xp = &xs[half * 8 * D];
    for (int dd = 0; dd < D; ++dd) {
        float w = W[dd * 96 + h];
#pragma unroll
        for (int r = 0; r < 8; ++r) acc[r] += xp[r * D + dd] * w;
    }
#pragma unroll
    for (int r = 0; r < 8; ++r) {
        int nn = n0 + half * 8 + r;
        if (nn < N) s[(size_t)nn * 96 + h] = silu_f(acc[r]);
    }
}

__global__ __launch_bounds__(192) void lin2_kernel(const float* __restrict__ s,
        const float* __restrict__ W1, const float* __restrict__ b1,
        const float* __restrict__ W2, const float* __restrict__ b2,
        float* __restrict__ o1, float* __restrict__ o2, int N) {
    __shared__ float xs[16 * 96];
    int t = threadIdx.x, half = t / 96, h = t - half * 96;
    int n0 = blockIdx.x * 16;
    for (int i = t; i < 16 * 96; i += 192) {
        int r = i / 96, c = i - r * 96, nn = n0 + r;
        xs[i] = (nn < N) ? s[(size_t)nn * 96 + c] : 0.f;
    }
    __syncthreads();
    const float* xp = &xs[half * 8 * 96];
    float a1[8], a2[8];
    float bb1 = b1[h];
#pragma unroll
    for (int r = 0; r < 8; ++r) a1[r] = bb1;
    if (W2) {
        float bb2 = b2[h];
#pragma unroll
        for (int r = 0; r < 8; ++r) a2[r] = bb2;
        for (int k = 0; k < 96; ++k) {
            float w1 = W1[k * 96 + h], w2 = W2[k * 96 + h];
#pragma unroll
            for (int r = 0; r < 8; ++r) { float v = xp[r * 96 + k]; a1[r] += v * w1; a2[r] += v * w2; }
        }
#pragma unroll
        for (int r = 0; r < 8; ++r) {
            int nn = n0 + half * 8 + r;
            if (nn < N) { o1[(size_t)nn * 96 + h] = a1[r]; o2[(size_t)nn * 96 + h] = a2[r]; }
        }
    } else {
        for (int k = 0; k < 96; ++k) {
            float w1 = W1[k * 96 + h];
#pragma unroll
            for (int r = 0; r < 8; ++r) a1[r] += xp[r * 96 + k] * w1;
        }
#pragma unroll
        for (int r = 0; r < 8; ++r) {
            int nn = n0 + half * 8 + r;
            if (nn < N) o1[(size_t)nn * 96 + h] = a1[r];
        }
    }
}

__global__ __launch_bounds__(192) void ssm2_kernel(float* __restrict__ sL,
        const float* __restrict__ Win, const float* __restrict__ b_in,
        const float* __restrict__ Wout, const float* __restrict__ bout, int N) {
    __shared__ float row[4 * 96];
    __shared__ float u[4 * 192];
    __shared__ float pu[4 * 96];
    int t = threadIdx.x;
    int n0 = blockIdx.x * 4;
    for (int i = t; i < 4 * 96; i += 192) {
        int r = i / 96, c = i - r * 96, nn = n0 + r;
        row[i] = (nn < N) ? sL[(size_t)nn * 96 + c] : 0.f;
    }
    __syncthreads();
    float acc[4]; float bb = b_in[t];
#pragma unroll
    for (int r = 0; r < 4; ++r) acc[r] = bb;
    for (int k = 0; k < 96; ++k) {
        float w = Win[k * 384 + t];
#pragma unroll
        for (int r = 0; r < 4; ++r) acc[r] += row[r * 96 + k] * w;
    }
#pragma unroll
    for (int r = 0; r < 4; ++r) u[r * 192 + t] = silu_f(acc[r]);
    __syncthreads();
    int half = t / 96, h = t - half * 96;
    float d[4] = {0.f, 0.f, 0.f, 0.f};
    int j0 = half * 96;
    for (int j = j0; j < j0 + 96; ++j) {
        float w = Wout[j * 96 + h];
#pragma unroll
        for (int r = 0; r < 4; ++r) d[r] += u[r * 192 + j] * w;
    }
    if (half == 1) {
#pragma unroll
        for (int r = 0; r < 4; ++r) pu[r * 96 + h] = d[r];
    }
    __syncthreads();
    if (half == 0) {
        float bo = bout[h];
#pragma unroll
        for (int r = 0; r < 4; ++r) {
            int nn = n0 + r;
            if (nn < N) sL[(size_t)nn * 96 + h] = row[r * 96 + h] + bo + d[r] + pu[r * 96 + h];
        }
    }
}

__global__ __launch_bounds__(192) void head2_kernel(const float* __restrict__ sL,
        const float* __restrict__ W1, const float* __restrict__ b1,
        const float* __restrict__ W2, const float* __restrict__ b2,
        float* __restrict__ out, int N) {
    __shared__ float buf[16 * 96];
    int t = threadIdx.x, half = t / 96, h = t - half * 96;
    int n0 = blockIdx.x * 16;
    for (int i = t; i < 16 * 96; i += 192) {
        int r = i / 96, c = i - r * 96, nn = n0 + r;
        buf[i] = (nn < N) ? sL[(size_t)nn * 96 + c] : 0.f;
    }
    __syncthreads();
    int rbase = half * 8;
    float a[8]; float bb = b1[h];
#pragma unroll
    for (int r = 0; r < 8; ++r) a[r] = bb;
    for (int k = 0; k < 96; ++k) {
        float w = W1[k * 96 + h];
#pragma unroll
        for (int r = 0; r < 8; ++r) a[r] += buf[(rbase + r) * 96 + k] * w;
    }
    __syncthreads();
#pragma unroll
    for (int r = 0; r < 8; ++r) buf[(rbase + r) * 96 + h] = silu_f(a[r]);
    __syncthreads();
    if (t < 48) {
        int r = t / 3, c = t - r * 3;
        float o = b2[c];
        for (int j = 0; j < 96; ++j) o += buf[r * 96 + j] * W2[j * 3 + c];
        int nn = n0 + r;
        if (nn < N) out[nn * 3 + c] = o;
    }
}

static inline int cdiv(int a, int b) { return (a + b - 1) / b; }

extern "C" void kernel_launch(void* const* d_in, const int* in_sizes, int n_in,
                              void* d_out, int out_size, void* d_ws, size_t ws_size,
                              hipStream_t stream) {
    const float* x_L   = (const float*)d_in[0];
    const float* pos_L = (const float*)d_in[1];
    const float* x_P   = (const float*)d_in[2];
    const float* pos_P = (const float*)d_in[3];
    const int* edge_L = (const int*)d_in[4];
    const int* edge_P = (const int*)d_in[5];
    const int* csrc   = (const int*)d_in[6];
    const int* ctgt   = (const int*)d_in[7];
    const float *Wemb_L = (const float*)d_in[8],  *bemb_L = (const float*)d_in[9];
    const float *Wl_L = (const float*)d_in[10], *bl_L = (const float*)d_in[11];
    const float *Wr_L = (const float*)d_in[12], *br_L = (const float*)d_in[13];
    const float *We_L = (const float*)d_in[14], *att_L = (const float*)d_in[15], *bias_L = (const float*)d_in[16];
    const float *Wemb_P = (const float*)d_in[17], *bemb_P = (const float*)d_in[18];
    const float *Wl_P = (const float*)d_in[19], *bl_P = (const float*)d_in[20];
    const float *Wr_P = (const float*)d_in[21], *br_P = (const float*)d_in[22];
    const float *We_P = (const float*)d_in[23], *att_P = (const float*)d_in[24], *bias_P = (const float*)d_in[25];
    const float *Win = (const float*)d_in[26], *b_in = (const float*)d_in[27];
    const float *Wout = (const float*)d_in[28], *bout = (const float*)d_in[29];
    const float *Wq = (const float*)d_in[30], *bq = (const float*)d_in[31];
    const float *Wk = (const float*)d_in[32], *bk = (const float*)d_in[33];
    const float *Wv = (const float*)d_in[34], *bv = (const float*)d_in[35];
    const float *W1 = (const float*)d_in[36], *b1 = (const float*)d_in[37];
    const float *W2 = (const float*)d_in[38], *b2 = (const float*)d_in[39];

    const int N_L = in_sizes[1] / 3;
    const int N_P = in_sizes[3] / 3;
    const int E_L = in_sizes[4] / 2;
    const int E_P = in_sizes[5] / 2;
    const int E_X = in_sizes[6];
    const int D_L = in_sizes[0] / N_L;
    const int D_P = in_sizes[2] / N_P;
    const int Emax = (E_L > E_P ? E_L : E_P);
    const int Nmax = N_L > N_P ? N_L : N_P;

    // workspace layout (4B units)
    float* ws     = (float*)d_ws;
    float* s_L    = ws;                                  // N_L*96
    float* s_P    = s_L + (size_t)N_L * 96;              // N_P*96
    float* xl     = s_P + (size_t)N_P * 96;              // N_P*96 (later qn)
    float* xr     = xl + (size_t)N_P * 96;               // N_P*96 (later kn)
    float* vn     = xr + (size_t)N_P * 96;               // N_P*96
    int2*  sd     = (int2*)(vn + (size_t)N_P * 96);      // Emax int2 (L then P, reused)
    int*   csrc_s = (int*)sd + 2 * (size_t)Emax;         // E_X ints
    float* clog_s = (float*)(csrc_s + (size_t)E_X);      // E_X floats
    float* T_L    = clog_s + (size_t)E_X;                // 1025*96
    float* T_P    = T_L + 1025 * 96;                     // 1025*96
    int*   rowptr = (int*)(T_P + 1025 * 96);             // Nmax+1
    int*   count  = rowptr + (size_t)Nmax + 1;           // Nmax
    int*   cursor = count + (size_t)Nmax;                // Nmax
    float* csc    = (float*)(cursor + (size_t)Nmax);     // 2

    // RBF@We lookup tables (independent of everything else)
    rbf_table_kernel<<<2050, 96, 0, stream>>>(We_L, We_P, T_L, T_P);

    // ---------------- L encoder ----------------
    embed2_kernel<<<cdiv(N_L, 16), 192, 0, stream>>>(x_L, Wemb_L, bemb_L, s_L, N_L, D_L);
    lin2_kernel<<<cdiv(N_L, 16), 192, 0, stream>>>(s_L, Wl_L, bl_L, Wr_L, br_L, xl, xr, N_L);
    fill_i<<<cdiv(N_L, 256), 256, 0, stream>>>(count, 0, N_L);
    hist_kernel<<<cdiv(E_L, 256), 256, 0, stream>>>(edge_L + E_L, count, E_L);
    scan_kernel<<<1, 1024, 0, stream>>>(count, rowptr, cursor, N_L);
    gat_pre_kernel<<<cdiv(E_L, 256), 256, 0, stream>>>(edge_L, edge_L + E_L, pos_L, cursor, sd, E_L);
    gat_v2_kernel<<<cdiv(N_L, 4), 256, 0, stream>>>(rowptr, sd, xl, xr, T_L, att_L, bias_L, s_L, N_L);

    // ---------------- P encoder ----------------
    embed2_kernel<<<cdiv(N_P, 16), 192, 0, stream>>>(x_P, Wemb_P, bemb_P, s_P, N_P, D_P);
    lin2_kernel<<<cdiv(N_P, 16), 192, 0, stream>>>(s_P, Wl_P, bl_P, Wr_P, br_P, xl, xr, N_P);
    fill_i<<<cdiv(N_P, 256), 256, 0, stream>>>(count, 0, N_P);
    hist_kernel<<<cdiv(E_P, 256), 256, 0, stream>>>(edge_P + E_P, count, E_P);
    scan_kernel<<<1, 1024, 0, stream>>>(count, rowptr, cursor, N_P);
    gat_pre_kernel<<<cdiv(E_P, 256), 256, 0, stream>>>(edge_P, edge_P + E_P, pos_P, cursor, sd, E_P);
    gat_v2_kernel<<<cdiv(N_P, 4), 256, 0, stream>>>(rowptr, sd, xl, xr, T_P, att_P, bias_P, s_P, N_P);

    // ---------------- SSM block (L) ----------------
    ssm2_kernel<<<cdiv(N_L, 4), 192, 0, stream>>>(s_L, Win, b_in, Wout, bout, N_L);

    // ---------------- cross attention ----------------
    lin2_kernel<<<cdiv(N_L, 16), 192, 0, stream>>>(s_L, Wq, bq, nullptr, nullptr, xl, nullptr, N_L);
    lin2_kernel<<<cdiv(N_P, 16), 192, 0, stream>>>(s_P, Wk, bk, Wv, bv, xr, vn, N_P);
    fill_i<<<cdiv(N_L, 256), 256, 0, stream>>>(count, 0, N_L);
    hist_kernel<<<cdiv(E_X, 256), 256, 0, stream>>>(ctgt, count, E_X);
    scan_kernel<<<1, 1024, 0, stream>>>(count, rowptr, cursor, N_L);
    cross_pre_kernel<<<cdiv(E_X, 256), 256, 0, stream>>>(csrc, ctgt, cursor, csrc_s, E_X);
    init_csc<<<1, 64, 0, stream>>>(csc);
    cross_logit_node_kernel<<<cdiv(N_L, 4), 256, 0, stream>>>(rowptr, csrc_s, xl, xr, clog_s, csc, N_L);
    cross_denom_kernel<<<cdiv(E_X, 256), 256, 0, stream>>>(clog_s, csc, E_X);
    cross_apply_node_kernel<<<cdiv(N_L, 4), 256, 0, stream>>>(rowptr, csrc_s, clog_s, vn, csc, s_L, N_L);

    // ---------------- head ----------------
    head2_kernel<<<cdiv(N_L, 16), 192, 0, stream>>>(s_L, W1, b1, W2, b2, (float*)d_out, N_L);
}

// Round 6
// 801.462 us; speedup vs baseline: 1.2326x; 1.2326x over previous
//
#include <hip/hip_runtime.h>

__device__ __forceinline__ float silu_f(float x) { return x / (1.f + __expf(-x)); }

__device__ __forceinline__ void atomicMaxF(float* addr, float val) {
    if (val >= 0.f) atomicMax((int*)addr, __float_as_int(val));
    else            atomicMin((unsigned int*)addr, __float_as_uint(val));
}

__global__ void fill_i(int* __restrict__ p, int v, int n) {
    int i = blockIdx.x * blockDim.x + threadIdx.x;
    if (i < n) p[i] = v;
}

__global__ void init_csc(float* __restrict__ csc) {
    if (threadIdx.x == 0) { csc[0] = -3.4e38f; csc[1] = 0.f; }
}

__global__ void hist_kernel(const int* __restrict__ tgt, int* __restrict__ count, int E) {
    int e = blockIdx.x * blockDim.x + threadIdx.x;
    if (e < E) atomicAdd(&count[tgt[e]], 1);
}

// single-block exclusive scan: count[0..n) -> rowptr[0..n], cursor[0..n)
__global__ __launch_bounds__(1024) void scan_kernel(const int* __restrict__ count,
                                                    int* __restrict__ rowptr,
                                                    int* __restrict__ cursor, int n) {
    __shared__ int part[1024];
    int t = threadIdx.x;
    int chunk = (n + 1023) >> 10;
    int beg = t * chunk, end = min(beg + chunk, n);
    int s = 0;
    for (int i = beg; i < end; ++i) s += count[i];
    part[t] = s; __syncthreads();
    for (int off = 1; off < 1024; off <<= 1) {
        int v = (t >= off) ? part[t - off] : 0;
        __syncthreads();
        part[t] += v;
        __syncthreads();
    }
    int run = (t == 0) ? 0 : part[t - 1];
    for (int i = beg; i < end; ++i) { int c = count[i]; rowptr[i] = run; cursor[i] = run; run += c; }
    if (end == n) rowptr[n] = run;
}

// GAT pre-pass: scatter (src, dist) into CSR slot of tgt
__global__ __launch_bounds__(256) void gat_pre_kernel(const int* __restrict__ src,
        const int* __restrict__ tgt, const float* __restrict__ pos,
        int* __restrict__ cursor, int2* __restrict__ sd, int E) {
    int e = blockIdx.x * blockDim.x + threadIdx.x;
    if (e >= E) return;
    int si = src[e], ti = tgt[e];
    float dx = pos[si * 3 + 0] - pos[ti * 3 + 0];
    float dy = pos[si * 3 + 1] - pos[ti * 3 + 1];
    float dz = pos[si * 3 + 2] - pos[ti * 3 + 2];
    float dist = sqrtf(dx * dx + dy * dy + dz * dz);
    int p = atomicAdd(&cursor[ti], 1);
    sd[p] = make_int2(si, __float_as_int(dist));
}

__global__ __launch_bounds__(256) void cross_pre_kernel(const int* __restrict__ csrc,
        const int* __restrict__ ctgt, int* __restrict__ cursor, int* __restrict__ csrc_s, int E) {
    int e = blockIdx.x * blockDim.x + threadIdx.x;
    if (e >= E) return;
    int p = atomicAdd(&cursor[ctgt[e]], 1);
    csrc_s[p] = csrc[e];
}

// Precompute T[i][h] = sum_g exp(-1.125*(d_i - (2/3)g)^2) * We[g][h], d_i = i/64, i in [0,1024].
__global__ __launch_bounds__(96) void rbf_table_kernel(const float* __restrict__ We_L,
        const float* __restrict__ We_P, float* __restrict__ T_L, float* __restrict__ T_P) {
    int b = blockIdx.x;
    const float* We = (b < 1025) ? We_L : We_P;
    float* T = (b < 1025) ? T_L : T_P;
    int i = (b < 1025) ? b : b - 1025;
    int h = threadIdx.x;
    float d = (float)i * 0.015625f;  // 1/64
    float acc = 0.f;
#pragma unroll
    for (int g = 0; g < 16; ++g) {
        float t = d - 0.66666667f * (float)g;
        acc += __expf(-1.125f * t * t) * We[g * 96 + h];
    }
    T[i * 96 + h] = acc;
}

// GATv2 v3: half-wave (32 lanes) per node, lane owns h in {l, l+32, l+64}.
// Unroll-by-4 batched prefetch + single-pass online softmax.
__global__ __launch_bounds__(256) void gat_v3_kernel(const int* __restrict__ rowptr,
        const int2* __restrict__ sd, const float* __restrict__ xl, const float* __restrict__ xr,
        const float* __restrict__ T, const float* __restrict__ att,
        const float* __restrict__ bias, float* __restrict__ s, int N) {
    int tid = threadIdx.x;
    int l = tid & 31;
    int n = blockIdx.x * 8 + (tid >> 5);
    if (n >= N) return;
    float att0 = att[l], att1 = att[32 + l], att2 = att[64 + l];
    size_t nb = (size_t)n * 96;
    float xr0 = xr[nb + l], xr1 = xr[nb + 32 + l], xr2 = xr[nb + 64 + l];
    int beg = rowptr[n], end = rowptr[n + 1];
    float m = -3.4e38f, d = 0.f, a0 = 0.f, a1 = 0.f, a2 = 0.f;
    for (int j = beg; j < end; j += 4) {
        float y0[4], y1[4], y2[4], t0[4], t1[4], t2[4], u0[4], u1[4], u2[4], ff[4];
#pragma unroll
        for (int k = 0; k < 4; ++k) {
            int jj = min(j + k, end - 1);
            int2 e = sd[jj];
            float dist = __int_as_float(e.y);
            float dt = fminf(dist * 64.f, 1023.f);
            int i = (int)dt;
            ff[k] = dt - (float)i;
            const float* tr = T + (size_t)i * 96;
            t0[k] = tr[l];      t1[k] = tr[32 + l];  t2[k] = tr[64 + l];
            u0[k] = tr[96 + l]; u1[k] = tr[128 + l]; u2[k] = tr[160 + l];
            const float* xp = xl + (size_t)e.x * 96;
            y0[k] = xp[l]; y1[k] = xp[32 + l]; y2[k] = xp[64 + l];
        }
        float lt[4];
#pragma unroll
        for (int k = 0; k < 4; ++k) {
            float v0 = y0[k] + xr0 + t0[k] + ff[k] * (u0[k] - t0[k]);
            float v1 = y1[k] + xr1 + t1[k] + ff[k] * (u1[k] - t1[k]);
            float v2 = y2[k] + xr2 + t2[k] + ff[k] * (u2[k] - t2[k]);
            v0 = fmaxf(v0, 0.f) + 0.2f * fminf(v0, 0.f);
            v1 = fmaxf(v1, 0.f) + 0.2f * fminf(v1, 0.f);
            v2 = fmaxf(v2, 0.f) + 0.2f * fminf(v2, 0.f);
            float t = v0 * att0 + v1 * att1 + v2 * att2;
#pragma unroll
            for (int off = 1; off < 32; off <<= 1) t += __shfl_xor(t, off, 64);
            lt[k] = (j + k < end) ? t : -3.4e38f;
        }
        float bm = fmaxf(fmaxf(lt[0], lt[1]), fmaxf(lt[2], lt[3]));
        float nm = fmaxf(m, bm);
        float sc = __expf(m - nm);
        d *= sc; a0 *= sc; a1 *= sc; a2 *= sc;
#pragma unroll
        for (int k = 0; k < 4; ++k) {
            float w = __expf(lt[k] - nm);
            d += w;
            a0 += w * y0[k]; a1 += w * y1[k]; a2 += w * y2[k];
        }
        m = nm;
    }
    float agg0 = (d > 0.f) ? a0 / d : 0.f;
    float agg1 = (d > 0.f) ? a1 / d : 0.f;
    float agg2 = (d > 0.f) ? a2 / d : 0.f;
    s[nb + l]      += silu_f(agg0 + bias[l]);
    s[nb + 32 + l] += silu_f(agg1 + bias[32 + l]);
    s[nb + 64 + l] += silu_f(agg2 + bias[64 + l]);
}

// cross logits v3: half-wave per node, unroll-4 prefetch of kn rows
__global__ __launch_bounds__(256) void cross_logit_v3_kernel(const int* __restrict__ rowptr,
        const int* __restrict__ csrc_s, const float* __restrict__ qn, const float* __restrict__ kn,
        float* __restrict__ clog_s, float* __restrict__ csc, int N) {
    int tid = threadIdx.x;
    int l = tid & 31;
    int n = blockIdx.x * 8 + (tid >> 5);
    if (n >= N) return;
    size_t nb = (size_t)n * 96;
    float q0 = qn[nb + l], q1 = qn[nb + 32 + l], q2 = qn[nb + 64 + l];
    int beg = rowptr[n], end = rowptr[n + 1];
    float mx = -3.4e38f;
    for (int j = beg; j < end; j += 4) {
        float k0[4], k1[4], k2[4];
#pragma unroll
        for (int k = 0; k < 4; ++k) {
            int jj = min(j + k, end - 1);
            const float* kp = kn + (size_t)csrc_s[jj] * 96;
            k0[k] = kp[l]; k1[k] = kp[32 + l]; k2[k] = kp[64 + l];
        }
#pragma unroll
        for (int k = 0; k < 4; ++k) {
            float t = q0 * k0[k] + q1 * k1[k] + q2 * k2[k];
#pragma unroll
            for (int off = 1; off < 32; off <<= 1) t += __shfl_xor(t, off, 64);
            t *= 0.125f;
            if (j + k < end) {
                if (l == 0) clog_s[j + k] = t;
                mx = fmaxf(mx, t);
            }
        }
    }
    if (l == 0 && end > beg) atomicMaxF(&csc[0], mx);
}

__global__ __launch_bounds__(256) void cross_denom_kernel(const float* __restrict__ clog_s,
                                                          float* __restrict__ csc, int E) {
    int e = blockIdx.x * blockDim.x + threadIdx.x;
    float a = 0.f;
    float mg = csc[0];
    if (e < E) a = __expf(clog_s[e] - mg);
    __shared__ float red[256];
    red[threadIdx.x] = a; __syncthreads();
    for (int s = 128; s > 0; s >>= 1) {
        if (threadIdx.x < s) red[threadIdx.x] += red[threadIdx.x + s];
        __syncthreads();
    }
    if (threadIdx.x == 0) atomicAdd(&csc[1], red[0]);
}

// cross apply v3: half-wave per node, unroll-4 prefetch of vn rows
__global__ __launch_bounds__(256) void cross_apply_v3_kernel(const int* __restrict__ rowptr,
        const int* __restrict__ csrc_s, const float* __restrict__ clog_s,
        const float* __restrict__ vn, const float* __restrict__ csc,
        float* __restrict__ sL, int N) {
    int tid = threadIdx.x;
    int l = tid & 31;
    int n = blockIdx.x * 8 + (tid >> 5);
    if (n >= N) return;
    int beg = rowptr[n], end = rowptr[n + 1];
    if (beg == end) return;
    float M = csc[0], invD = 1.f / csc[1];
    float a0 = 0.f, a1 = 0.f, a2 = 0.f;
    for (int j = beg; j < end; j += 4) {
        float v0[4], v1[4], v2[4], w[4];
#pragma unroll
        for (int k = 0; k < 4; ++k) {
            int jj = min(j + k, end - 1);
            const float* vp = vn + (size_t)csrc_s[jj] * 96;
            v0[k] = vp[l]; v1[k] = vp[32 + l]; v2[k] = vp[64 + l];
            w[k] = (j + k < end) ? __expf(clog_s[jj] - M) : 0.f;
        }
#pragma unroll
        for (int k = 0; k < 4; ++k) {
            a0 += w[k] * v0[k]; a1 += w[k] * v1[k]; a2 += w[k] * v2[k];
        }
    }
    size_t nb = (size_t)n * 96;
    sL[nb + l]      += a0 * invD;
    sL[nb + 32 + l] += a1 * invD;
    sL[nb + 64 + l] += a2 * invD;
}

// ---------- row-blocked dense kernels ----------

__global__ __launch_bounds__(192) void embed2_kernel(const float* __restrict__ x,
        const float* __restrict__ W, const float* __restrict__ b,
        float* __restrict__ s, int N, int D) {
    __shared__ float xs[16 * 167];
    int t = threadIdx.x, half = t / 96, h = t - half * 96;
    int n0 = blockIdx.x * 16;
    for (int i = t; i < 16 * D; i += 192) {
        int r = i / D, dd = i - r * D, nn = n0 + r;
        xs[i] = (nn < N) ? x[(size_t)nn * D + dd] : 0.f;
    }
    __syncthreads();
    float acc[8]; float bb = b[h];
#pragma unroll
    for (int r = 0; r < 8; ++r) acc[r] = bb;
    const float* xp = &xs[half * 8 * D];
    for (int dd = 0; dd < D; ++dd) {
        float w = W[dd * 96 + h];
#pragma unroll
        for (int r = 0; r < 8; ++r) acc[r] += xp[r * D + dd] * w;
    }
#pragma unroll
    for (int r = 0; r < 8; ++r) {
        int nn = n0 + half * 8 + r;
        if (nn < N) s[(size_t)nn * 96 + h] = silu_f(acc[r]);
    }
}

__global__ __launch_bounds__(192) void lin2_kernel(const float* __restrict__ s,
        const float* __restrict__ W1, const float* __restrict__ b1,
        const float* __restrict__ W2, const float* __restrict__ b2,
        float* __restrict__ o1, float* __restrict__ o2, int N) {
    __shared__ float xs[16 * 96];
    int t = threadIdx.x, half = t / 96, h = t - half * 96;
    int n0 = blockIdx.x * 16;
    for (int i = t; i < 16 * 96; i += 192) {
        int r = i / 96, c = i - r * 96, nn = n0 + r;
        xs[i] = (nn < N) ? s[(size_t)nn * 96 + c] : 0.f;
    }
    __syncthreads();
    const float* xp = &xs[half * 8 * 96];
    float a1[8], a2[8];
    float bb1 = b1[h];
#pragma unroll
    for (int r = 0; r < 8; ++r) a1[r] = bb1;
    if (W2) {
        float bb2 = b2[h];
#pragma unroll
        for (int r = 0; r < 8; ++r) a2[r] = bb2;
        for (int k = 0; k < 96; ++k) {
            float w1 = W1[k * 96 + h], w2 = W2[k * 96 + h];
#pragma unroll
            for (int r = 0; r < 8; ++r) { float v = xp[r * 96 + k]; a1[r] += v * w1; a2[r] += v * w2; }
        }
#pragma unroll
        for (int r = 0; r < 8; ++r) {
            int nn = n0 + half * 8 + r;
            if (nn < N) { o1[(size_t)nn * 96 + h] = a1[r]; o2[(size_t)nn * 96 + h] = a2[r]; }
        }
    } else {
        for (int k = 0; k < 96; ++k) {
            float w1 = W1[k * 96 + h];
#pragma unroll
            for (int r = 0; r < 8; ++r) a1[r] += xp[r * 96 + k] * w1;
        }
#pragma unroll
        for (int r = 0; r < 8; ++r) {
            int nn = n0 + half * 8 + r;
            if (nn < N) o1[(size_t)nn * 96 + h] = a1[r];
        }
    }
}

__global__ __launch_bounds__(192) void ssm2_kernel(float* __restrict__ sL,
        const float* __restrict__ Win, const float* __restrict__ b_in,
        const float* __restrict__ Wout, const float* __restrict__ bout, int N) {
    __shared__ float row[4 * 96];
    __shared__ float u[4 * 192];
    __shared__ float pu[4 * 96];
    int t = threadIdx.x;
    int n0 = blockIdx.x * 4;
    for (int i = t; i < 4 * 96; i += 192) {
        int r = i / 96, c = i - r * 96, nn = n0 + r;
        row[i] = (nn < N) ? sL[(size_t)nn * 96 + c] : 0.f;
    }
    __syncthreads();
    float acc[4]; float bb = b_in[t];
#pragma unroll
    for (int r = 0; r < 4; ++r) acc[r] = bb;
    for (int k = 0; k < 96; ++k) {
        float w = Win[k * 384 + t];
#pragma unroll
        for (int r = 0; r < 4; ++r) acc[r] += row[r * 96 + k] * w;
    }
#pragma unroll
    for (int r = 0; r < 4; ++r) u[r * 192 + t] = silu_f(acc[r]);
    __syncthreads();
    int half = t / 96, h = t - half * 96;
    float d[4] = {0.f, 0.f, 0.f, 0.f};
    int j0 = half * 96;
    for (int j = j0; j < j0 + 96; ++j) {
        float w = Wout[j * 96 + h];
#pragma unroll
        for (int r = 0; r < 4; ++r) d[r] += u[r * 192 + j] * w;
    }
    if (half == 1) {
#pragma unroll
        for (int r = 0; r < 4; ++r) pu[r * 96 + h] = d[r];
    }
    __syncthreads();
    if (half == 0) {
        float bo = bout[h];
#pragma unroll
        for (int r = 0; r < 4; ++r) {
            int nn = n0 + r;
            if (nn < N) sL[(size_t)nn * 96 + h] = row[r * 96 + h] + bo + d[r] + pu[r * 96 + h];
        }
    }
}

__global__ __launch_bounds__(192) void head2_kernel(const float* __restrict__ sL,
        const float* __restrict__ W1, const float* __restrict__ b1,
        const float* __restrict__ W2, const float* __restrict__ b2,
        float* __restrict__ out, int N) {
    __shared__ float buf[16 * 96];
    int t = threadIdx.x, half = t / 96, h = t - half * 96;
    int n0 = blockIdx.x * 16;
    for (int i = t; i < 16 * 96; i += 192) {
        int r = i / 96, c = i - r * 96, nn = n0 + r;
        buf[i] = (nn < N) ? sL[(size_t)nn * 96 + c] : 0.f;
    }
    __syncthreads();
    int rbase = half * 8;
    float a[8]; float bb = b1[h];
#pragma unroll
    for (int r = 0; r < 8; ++r) a[r] = bb;
    for (int k = 0; k < 96; ++k) {
        float w = W1[k * 96 + h];
#pragma unroll
        for (int r = 0; r < 8; ++r) a[r] += buf[(rbase + r) * 96 + k] * w;
    }
    __syncthreads();
#pragma unroll
    for (int r = 0; r < 8; ++r) buf[(rbase + r) * 96 + h] = silu_f(a[r]);
    __syncthreads();
    if (t < 48) {
        int r = t / 3, c = t - r * 3;
        float o = b2[c];
        for (int j = 0; j < 96; ++j) o += buf[r * 96 + j] * W2[j * 3 + c];
        int nn = n0 + r;
        if (nn < N) out[nn * 3 + c] = o;
    }
}

static inline int cdiv(int a, int b) { return (a + b - 1) / b; }

extern "C" void kernel_launch(void* const* d_in, const int* in_sizes, int n_in,
                              void* d_out, int out_size, void* d_ws, size_t ws_size,
                              hipStream_t stream) {
    const float* x_L   = (const float*)d_in[0];
    const float* pos_L = (const float*)d_in[1];
    const float* x_P   = (const float*)d_in[2];
    const float* pos_P = (const float*)d_in[3];
    const int* edge_L = (const int*)d_in[4];
    const int* edge_P = (const int*)d_in[5];
    const int* csrc   = (const int*)d_in[6];
    const int* ctgt   = (const int*)d_in[7];
    const float *Wemb_L = (const float*)d_in[8],  *bemb_L = (const float*)d_in[9];
    const float *Wl_L = (const float*)d_in[10], *bl_L = (const float*)d_in[11];
    const float *Wr_L = (const float*)d_in[12], *br_L = (const float*)d_in[13];
    const float *We_L = (const float*)d_in[14], *att_L = (const float*)d_in[15], *bias_L = (const float*)d_in[16];
    const float *Wemb_P = (const float*)d_in[17], *bemb_P = (const float*)d_in[18];
    const float *Wl_P = (const float*)d_in[19], *bl_P = (const float*)d_in[20];
    const float *Wr_P = (const float*)d_in[21], *br_P = (const float*)d_in[22];
    const float *We_P = (const float*)d_in[23], *att_P = (const float*)d_in[24], *bias_P = (const float*)d_in[25];
    const float *Win = (const float*)d_in[26], *b_in = (const float*)d_in[27];
    const float *Wout = (const float*)d_in[28], *bout = (const float*)d_in[29];
    const float *Wq = (const float*)d_in[30], *bq = (const float*)d_in[31];
    const float *Wk = (const float*)d_in[32], *bk = (const float*)d_in[33];
    const float *Wv = (const float*)d_in[34], *bv = (const float*)d_in[35];
    const float *W1 = (const float*)d_in[36], *b1 = (const float*)d_in[37];
    const float *W2 = (const float*)d_in[38], *b2 = (const float*)d_in[39];

    const int N_L = in_sizes[1] / 3;
    const int N_P = in_sizes[3] / 3;
    const int E_L = in_sizes[4] / 2;
    const int E_P = in_sizes[5] / 2;
    const int E_X = in_sizes[6];
    const int D_L = in_sizes[0] / N_L;
    const int D_P = in_sizes[2] / N_P;
    const int Emax = (E_L > E_P ? E_L : E_P);
    const int Nmax = N_L > N_P ? N_L : N_P;

    // workspace layout (4B units)
    float* ws     = (float*)d_ws;
    float* s_L    = ws;                                  // N_L*96
    float* s_P    = s_L + (size_t)N_L * 96;              // N_P*96
    float* xl     = s_P + (size_t)N_P * 96;              // N_P*96 (later qn)
    float* xr     = xl + (size_t)N_P * 96;               // N_P*96 (later kn)
    float* vn     = xr + (size_t)N_P * 96;               // N_P*96
    int2*  sd     = (int2*)(vn + (size_t)N_P * 96);      // Emax int2 (L then P, reused)
    int*   csrc_s = (int*)sd + 2 * (size_t)Emax;         // E_X ints
    float* clog_s = (float*)(csrc_s + (size_t)E_X);      // E_X floats
    float* T_L    = clog_s + (size_t)E_X;                // 1025*96
    float* T_P    = T_L + 1025 * 96;                     // 1025*96
    int*   rowptr = (int*)(T_P + 1025 * 96);             // Nmax+1
    int*   count  = rowptr + (size_t)Nmax + 1;           // Nmax
    int*   cursor = count + (size_t)Nmax;                // Nmax
    float* csc    = (float*)(cursor + (size_t)Nmax);     // 2

    // RBF@We lookup tables (independent of everything else)
    rbf_table_kernel<<<2050, 96, 0, stream>>>(We_L, We_P, T_L, T_P);

    // ---------------- L encoder ----------------
    embed2_kernel<<<cdiv(N_L, 16), 192, 0, stream>>>(x_L, Wemb_L, bemb_L, s_L, N_L, D_L);
    lin2_kernel<<<cdiv(N_L, 16), 192, 0, stream>>>(s_L, Wl_L, bl_L, Wr_L, br_L, xl, xr, N_L);
    fill_i<<<cdiv(N_L, 256), 256, 0, stream>>>(count, 0, N_L);
    hist_kernel<<<cdiv(E_L, 256), 256, 0, stream>>>(edge_L + E_L, count, E_L);
    scan_kernel<<<1, 1024, 0, stream>>>(count, rowptr, cursor, N_L);
    gat_pre_kernel<<<cdiv(E_L, 256), 256, 0, stream>>>(edge_L, edge_L + E_L, pos_L, cursor, sd, E_L);
    gat_v3_kernel<<<cdiv(N_L, 8), 256, 0, stream>>>(rowptr, sd, xl, xr, T_L, att_L, bias_L, s_L, N_L);

    // ---------------- P encoder ----------------
    embed2_kernel<<<cdiv(N_P, 16), 192, 0, stream>>>(x_P, Wemb_P, bemb_P, s_P, N_P, D_P);
    lin2_kernel<<<cdiv(N_P, 16), 192, 0, stream>>>(s_P, Wl_P, bl_P, Wr_P, br_P, xl, xr, N_P);
    fill_i<<<cdiv(N_P, 256), 256, 0, stream>>>(count, 0, N_P);
    hist_kernel<<<cdiv(E_P, 256), 256, 0, stream>>>(edge_P + E_P, count, E_P);
    scan_kernel<<<1, 1024, 0, stream>>>(count, rowptr, cursor, N_P);
    gat_pre_kernel<<<cdiv(E_P, 256), 256, 0, stream>>>(edge_P, edge_P + E_P, pos_P, cursor, sd, E_P);
    gat_v3_kernel<<<cdiv(N_P, 8), 256, 0, stream>>>(rowptr, sd, xl, xr, T_P, att_P, bias_P, s_P, N_P);

    // ---------------- SSM block (L) ----------------
    ssm2_kernel<<<cdiv(N_L, 4), 192, 0, stream>>>(s_L, Win, b_in, Wout, bout, N_L);

    // ---------------- cross attention ----------------
    lin2_kernel<<<cdiv(N_L, 16), 192, 0, stream>>>(s_L, Wq, bq, nullptr, nullptr, xl, nullptr, N_L);
    lin2_kernel<<<cdiv(N_P, 16), 192, 0, stream>>>(s_P, Wk, bk, Wv, bv, xr, vn, N_P);
    fill_i<<<cdiv(N_L, 256), 256, 0, stream>>>(count, 0, N_L);
    hist_kernel<<<cdiv(E_X, 256), 256, 0, stream>>>(ctgt, count, E_X);
    scan_kernel<<<1, 1024, 0, stream>>>(count, rowptr, cursor, N_L);
    cross_pre_kernel<<<cdiv(E_X, 256), 256, 0, stream>>>(csrc, ctgt, cursor, csrc_s, E_X);
    init_csc<<<1, 64, 0, stream>>>(csc);
    cross_logit_v3_kernel<<<cdiv(N_L, 8), 256, 0, stream>>>(rowptr, csrc_s, xl, xr, clog_s, csc, N_L);
    cross_denom_kernel<<<cdiv(E_X, 256), 256, 0, stream>>>(clog_s, csc, E_X);
    cross_apply_v3_kernel<<<cdiv(N_L, 8), 256, 0, stream>>>(rowptr, csrc_s, clog_s, vn, csc, s_L, N_L);

    // ---------------- head ----------------
    head2_kernel<<<cdiv(N_L, 16), 192, 0, stream>>>(s_L, W1, b1, W2, b2, (float*)d_out, N_L);
}

// Round 7
// 736.675 us; speedup vs baseline: 1.3410x; 1.0879x over previous
//
#include <hip/hip_runtime.h>

__device__ __forceinline__ float silu_f(float x) { return x / (1.f + __expf(-x)); }

__device__ __forceinline__ void atomicMaxF(float* addr, float val) {
    if (val >= 0.f) atomicMax((int*)addr, __float_as_int(val));
    else            atomicMin((unsigned int*)addr, __float_as_uint(val));
}

__global__ void fill_i(int* __restrict__ p, int v, int n) {
    int i = blockIdx.x * blockDim.x + threadIdx.x;
    if (i < n) p[i] = v;
}

__global__ void init_csc(float* __restrict__ csc) {
    if (threadIdx.x == 0) { csc[0] = -3.4e38f; csc[1] = 0.f; }
}

__global__ void hist_kernel(const int* __restrict__ tgt, int* __restrict__ count, int E) {
    int e = blockIdx.x * blockDim.x + threadIdx.x;
    if (e < E) atomicAdd(&count[tgt[e]], 1);
}

// ---- hierarchical scan: A) per-block sums, B) tiny top scan, C) apply ----
__global__ __launch_bounds__(256) void scan_blocksum_kernel(const int* __restrict__ count,
                                                            int* __restrict__ bsum, int n) {
    int b = blockIdx.x, t = threadIdx.x;
    int base = b * 4096 + t * 16;
    int s = 0;
#pragma unroll
    for (int k = 0; k < 16; ++k) {
        int idx = base + k;
        s += (idx < n) ? count[idx] : 0;
    }
#pragma unroll
    for (int off = 1; off < 64; off <<= 1) s += __shfl_xor(s, off, 64);
    __shared__ int ws[4];
    int lane = t & 63, wid = t >> 6;
    if (lane == 0) ws[wid] = s;
    __syncthreads();
    if (t == 0) bsum[b] = ws[0] + ws[1] + ws[2] + ws[3];
}

__global__ void scan_top_kernel(int* __restrict__ bsum, int nb) {
    if (threadIdx.x == 0) {
        int run = 0;
        for (int i = 0; i < nb; ++i) { int c = bsum[i]; bsum[i] = run; run += c; }
    }
}

__global__ __launch_bounds__(256) void scan_apply_kernel(const int* __restrict__ count,
        const int* __restrict__ bsum, int* __restrict__ rowptr, int* __restrict__ cursor,
        int n, int E) {
    int b = blockIdx.x, t = threadIdx.x;
    int base = b * 4096 + t * 16;
    int v[16];
    int s = 0;
#pragma unroll
    for (int k = 0; k < 16; ++k) {
        int idx = base + k;
        v[k] = (idx < n) ? count[idx] : 0;
        s += v[k];
    }
    int lane = t & 63, wid = t >> 6;
    int inc = s;
#pragma unroll
    for (int off = 1; off < 64; off <<= 1) {
        int o = __shfl_up(inc, off, 64);
        if (lane >= off) inc += o;
    }
    __shared__ int ws[4];
    if (lane == 63) ws[wid] = inc;
    __syncthreads();
    int woff = 0;
    for (int w = 0; w < wid; ++w) woff += ws[w];
    int prefix = bsum[b] + woff + (inc - s);
#pragma unroll
    for (int k = 0; k < 16; ++k) {
        int idx = base + k;
        if (idx < n) { rowptr[idx] = prefix; cursor[idx] = prefix; prefix += v[k]; }
    }
    if (b == 0 && t == 0) rowptr[n] = E;
}

// GAT pre-pass: scatter (src, dist) into CSR slot of tgt
__global__ __launch_bounds__(256) void gat_pre_kernel(const int* __restrict__ src,
        const int* __restrict__ tgt, const float* __restrict__ pos,
        int* __restrict__ cursor, int2* __restrict__ sd, int E) {
    int e = blockIdx.x * blockDim.x + threadIdx.x;
    if (e >= E) return;
    int si = src[e], ti = tgt[e];
    float dx = pos[si * 3 + 0] - pos[ti * 3 + 0];
    float dy = pos[si * 3 + 1] - pos[ti * 3 + 1];
    float dz = pos[si * 3 + 2] - pos[ti * 3 + 2];
    float dist = sqrtf(dx * dx + dy * dy + dz * dz);
    int p = atomicAdd(&cursor[ti], 1);
    sd[p] = make_int2(si, __float_as_int(dist));
}

__global__ __launch_bounds__(256) void cross_pre_kernel(const int* __restrict__ csrc,
        const int* __restrict__ ctgt, int* __restrict__ cursor, int* __restrict__ csrc_s, int E) {
    int e = blockIdx.x * blockDim.x + threadIdx.x;
    if (e >= E) return;
    int p = atomicAdd(&cursor[ctgt[e]], 1);
    csrc_s[p] = csrc[e];
}

// Precompute T[i][h] = sum_g exp(-1.125*(d_i - (2/3)g)^2) * We[g][h], d_i = i/64, i in [0,1024].
__global__ __launch_bounds__(96) void rbf_table_kernel(const float* __restrict__ We_L,
        const float* __restrict__ We_P, float* __restrict__ T_L, float* __restrict__ T_P) {
    int b = blockIdx.x;
    const float* We = (b < 1025) ? We_L : We_P;
    float* T = (b < 1025) ? T_L : T_P;
    int i = (b < 1025) ? b : b - 1025;
    int h = threadIdx.x;
    float d = (float)i * 0.015625f;  // 1/64
    float acc = 0.f;
#pragma unroll
    for (int g = 0; g < 16; ++g) {
        float t = d - 0.66666667f * (float)g;
        acc += __expf(-1.125f * t * t) * We[g * 96 + h];
    }
    T[i * 96 + h] = acc;
}

// GATv2 v3: half-wave (32 lanes) per node, lane owns h in {l, l+32, l+64}.
// Unroll-by-4 batched prefetch + single-pass online softmax.
__global__ __launch_bounds__(256) void gat_v3_kernel(const int* __restrict__ rowptr,
        const int2* __restrict__ sd, const float* __restrict__ xl, const float* __restrict__ xr,
        const float* __restrict__ T, const float* __restrict__ att,
        const float* __restrict__ bias, float* __restrict__ s, int N) {
    int tid = threadIdx.x;
    int l = tid & 31;
    int n = blockIdx.x * 8 + (tid >> 5);
    if (n >= N) return;
    float att0 = att[l], att1 = att[32 + l], att2 = att[64 + l];
    size_t nb = (size_t)n * 96;
    float xr0 = xr[nb + l], xr1 = xr[nb + 32 + l], xr2 = xr[nb + 64 + l];
    int beg = rowptr[n], end = rowptr[n + 1];
    float m = -3.4e38f, d = 0.f, a0 = 0.f, a1 = 0.f, a2 = 0.f;
    for (int j = beg; j < end; j += 4) {
        float y0[4], y1[4], y2[4], t0[4], t1[4], t2[4], u0[4], u1[4], u2[4], ff[4];
#pragma unroll
        for (int k = 0; k < 4; ++k) {
            int jj = min(j + k, end - 1);
            int2 e = sd[jj];
            float dist = __int_as_float(e.y);
            float dt = fminf(dist * 64.f, 1023.f);
            int i = (int)dt;
            ff[k] = dt - (float)i;
            const float* tr = T + (size_t)i * 96;
            t0[k] = tr[l];      t1[k] = tr[32 + l];  t2[k] = tr[64 + l];
            u0[k] = tr[96 + l]; u1[k] = tr[128 + l]; u2[k] = tr[160 + l];
            const float* xp = xl + (size_t)e.x * 96;
            y0[k] = xp[l]; y1[k] = xp[32 + l]; y2[k] = xp[64 + l];
        }
        float lt[4];
#pragma unroll
        for (int k = 0; k < 4; ++k) {
            float v0 = y0[k] + xr0 + t0[k] + ff[k] * (u0[k] - t0[k]);
            float v1 = y1[k] + xr1 + t1[k] + ff[k] * (u1[k] - t1[k]);
            float v2 = y2[k] + xr2 + t2[k] + ff[k] * (u2[k] - t2[k]);
            v0 = fmaxf(v0, 0.f) + 0.2f * fminf(v0, 0.f);
            v1 = fmaxf(v1, 0.f) + 0.2f * fminf(v1, 0.f);
            v2 = fmaxf(v2, 0.f) + 0.2f * fminf(v2, 0.f);
            float t = v0 * att0 + v1 * att1 + v2 * att2;
#pragma unroll
            for (int off = 1; off < 32; off <<= 1) t += __shfl_xor(t, off, 64);
            lt[k] = (j + k < end) ? t : -3.4e38f;
        }
        float bm = fmaxf(fmaxf(lt[0], lt[1]), fmaxf(lt[2], lt[3]));
        float nm = fmaxf(m, bm);
        float sc = __expf(m - nm);
        d *= sc; a0 *= sc; a1 *= sc; a2 *= sc;
#pragma unroll
        for (int k = 0; k < 4; ++k) {
            float w = __expf(lt[k] - nm);
            d += w;
            a0 += w * y0[k]; a1 += w * y1[k]; a2 += w * y2[k];
        }
        m = nm;
    }
    float agg0 = (d > 0.f) ? a0 / d : 0.f;
    float agg1 = (d > 0.f) ? a1 / d : 0.f;
    float agg2 = (d > 0.f) ? a2 / d : 0.f;
    s[nb + l]      += silu_f(agg0 + bias[l]);
    s[nb + 32 + l] += silu_f(agg1 + bias[32 + l]);
    s[nb + 64 + l] += silu_f(agg2 + bias[64 + l]);
}

// cross logits v3: half-wave per node, unroll-4 prefetch of kn rows
__global__ __launch_bounds__(256) void cross_logit_v3_kernel(const int* __restrict__ rowptr,
        const int* __restrict__ csrc_s, const float* __restrict__ qn, const float* __restrict__ kn,
        float* __restrict__ clog_s, float* __restrict__ csc, int N) {
    int tid = threadIdx.x;
    int l = tid & 31;
    int n = blockIdx.x * 8 + (tid >> 5);
    if (n >= N) return;
    size_t nb = (size_t)n * 96;
    float q0 = qn[nb + l], q1 = qn[nb + 32 + l], q2 = qn[nb + 64 + l];
    int beg = rowptr[n], end = rowptr[n + 1];
    float mx = -3.4e38f;
    for (int j = beg; j < end; j += 4) {
        float k0[4], k1[4], k2[4];
#pragma unroll
        for (int k = 0; k < 4; ++k) {
            int jj = min(j + k, end - 1);
            const float* kp = kn + (size_t)csrc_s[jj] * 96;
            k0[k] = kp[l]; k1[k] = kp[32 + l]; k2[k] = kp[64 + l];
        }
#pragma unroll
        for (int k = 0; k < 4; ++k) {
            float t = q0 * k0[k] + q1 * k1[k] + q2 * k2[k];
#pragma unroll
            for (int off = 1; off < 32; off <<= 1) t += __shfl_xor(t, off, 64);
            t *= 0.125f;
            if (j + k < end) {
                if (l == 0) clog_s[j + k] = t;
                mx = fmaxf(mx, t);
            }
        }
    }
    if (l == 0 && end > beg) atomicMaxF(&csc[0], mx);
}

__global__ __launch_bounds__(256) void cross_denom_kernel(const float* __restrict__ clog_s,
                                                          float* __restrict__ csc, int E) {
    int e = blockIdx.x * blockDim.x + threadIdx.x;
    float a = 0.f;
    float mg = csc[0];
    if (e < E) a = __expf(clog_s[e] - mg);
    __shared__ float red[256];
    red[threadIdx.x] = a; __syncthreads();
    for (int s = 128; s > 0; s >>= 1) {
        if (threadIdx.x < s) red[threadIdx.x] += red[threadIdx.x + s];
        __syncthreads();
    }
    if (threadIdx.x == 0) atomicAdd(&csc[1], red[0]);
}

// cross apply v3: half-wave per node, unroll-4 prefetch of vn rows
__global__ __launch_bounds__(256) void cross_apply_v3_kernel(const int* __restrict__ rowptr,
        const int* __restrict__ csrc_s, const float* __restrict__ clog_s,
        const float* __restrict__ vn, const float* __restrict__ csc,
        float* __restrict__ sL, int N) {
    int tid = threadIdx.x;
    int l = tid & 31;
    int n = blockIdx.x * 8 + (tid >> 5);
    if (n >= N) return;
    int beg = rowptr[n], end = rowptr[n + 1];
    if (beg == end) return;
    float M = csc[0], invD = 1.f / csc[1];
    float a0 = 0.f, a1 = 0.f, a2 = 0.f;
    for (int j = beg; j < end; j += 4) {
        float v0[4], v1[4], v2[4], w[4];
#pragma unroll
        for (int k = 0; k < 4; ++k) {
            int jj = min(j + k, end - 1);
            const float* vp = vn + (size_t)csrc_s[jj] * 96;
            v0[k] = vp[l]; v1[k] = vp[32 + l]; v2[k] = vp[64 + l];
            w[k] = (j + k < end) ? __expf(clog_s[jj] - M) : 0.f;
        }
#pragma unroll
        for (int k = 0; k < 4; ++k) {
            a0 += w[k] * v0[k]; a1 += w[k] * v1[k]; a2 += w[k] * v2[k];
        }
    }
    size_t nb = (size_t)n * 96;
    sL[nb + l]      += a0 * invD;
    sL[nb + 32 + l] += a1 * invD;
    sL[nb + 64 + l] += a2 * invD;
}

// ---------- row-blocked dense kernels ----------

__global__ __launch_bounds__(192) void embed2_kernel(const float* __restrict__ x,
        const float* __restrict__ W, const float* __restrict__ b,
        float* __restrict__ s, int N, int D) {
    __shared__ float xs[16 * 167];
    int t = threadIdx.x, half = t / 96, h = t - half * 96;
    int n0 = blockIdx.x * 16;
    for (int i = t; i < 16 * D; i += 192) {
        int r = i / D, dd = i - r * D, nn = n0 + r;
        xs[i] = (nn < N) ? x[(size_t)nn * D + dd] : 0.f;
    }
    __syncthreads();
    float acc[8]; float bb = b[h];
#pragma unroll
    for (int r = 0; r < 8; ++r) acc[r] = bb;
    const float* xp = &xs[half * 8 * D];
    for (int dd = 0; dd < D; ++dd) {
        float w = W[dd * 96 + h];
#pragma unroll
        for (int r = 0; r < 8; ++r) acc[r] += xp[r * D + dd] * w;
    }
#pragma unroll
    for (int r = 0; r < 8; ++r) {
        int nn = n0 + half * 8 + r;
        if (nn < N) s[(size_t)nn * 96 + h] = silu_f(acc[r]);
    }
}

__global__ __launch_bounds__(192) void lin2_kernel(const float* __restrict__ s,
        const float* __restrict__ W1, const float* __restrict__ b1,
        const float* __restrict__ W2, const float* __restrict__ b2,
        float* __restrict__ o1, float* __restrict__ o2, int N) {
    __shared__ float xs[16 * 96];
    int t = threadIdx.x, half = t / 96, h = t - half * 96;
    int n0 = blockIdx.x * 16;
    for (int i = t; i < 16 * 96; i += 192) {
        int r = i / 96, c = i - r * 96, nn = n0 + r;
        xs[i] = (nn < N) ? s[(size_t)nn * 96 + c] : 0.f;
    }
    __syncthreads();
    const float* xp = &xs[half * 8 * 96];
    float a1[8], a2[8];
    float bb1 = b1[h];
#pragma unroll
    for (int r = 0; r < 8; ++r) a1[r] = bb1;
    if (W2) {
        float bb2 = b2[h];
#pragma unroll
        for (int r = 0; r < 8; ++r) a2[r] = bb2;
        for (int k = 0; k < 96; ++k) {
            float w1 = W1[k * 96 + h], w2 = W2[k * 96 + h];
#pragma unroll
            for (int r = 0; r < 8; ++r) { float v = xp[r * 96 + k]; a1[r] += v * w1; a2[r] += v * w2; }
        }
#pragma unroll
        for (int r = 0; r < 8; ++r) {
            int nn = n0 + half * 8 + r;
            if (nn < N) { o1[(size_t)nn * 96 + h] = a1[r]; o2[(size_t)nn * 96 + h] = a2[r]; }
        }
    } else {
        for (int k = 0; k < 96; ++k) {
            float w1 = W1[k * 96 + h];
#pragma unroll
            for (int r = 0; r < 8; ++r) a1[r] += xp[r * 96 + k] * w1;
        }
#pragma unroll
        for (int r = 0; r < 8; ++r) {
            int nn = n0 + half * 8 + r;
            if (nn < N) o1[(size_t)nn * 96 + h] = a1[r];
        }
    }
}

__global__ __launch_bounds__(192) void ssm2_kernel(float* __restrict__ sL,
        const float* __restrict__ Win, const float* __restrict__ b_in,
        const float* __restrict__ Wout, const float* __restrict__ bout, int N) {
    __shared__ float row[4 * 96];
    __shared__ float u[4 * 192];
    __shared__ float pu[4 * 96];
    int t = threadIdx.x;
    int n0 = blockIdx.x * 4;
    for (int i = t; i < 4 * 96; i += 192) {
        int r = i / 96, c = i - r * 96, nn = n0 + r;
        row[i] = (nn < N) ? sL[(size_t)nn * 96 + c] : 0.f;
    }
    __syncthreads();
    float acc[4]; float bb = b_in[t];
#pragma unroll
    for (int r = 0; r < 4; ++r) acc[r] = bb;
    for (int k = 0; k < 96; ++k) {
        float w = Win[k * 384 + t];
#pragma unroll
        for (int r = 0; r < 4; ++r) acc[r] += row[r * 96 + k] * w;
    }
#pragma unroll
    for (int r = 0; r < 4; ++r) u[r * 192 + t] = silu_f(acc[r]);
    __syncthreads();
    int half = t / 96, h = t - half * 96;
    float d[4] = {0.f, 0.f, 0.f, 0.f};
    int j0 = half * 96;
    for (int j = j0; j < j0 + 96; ++j) {
        float w = Wout[j * 96 + h];
#pragma unroll
        for (int r = 0; r < 4; ++r) d[r] += u[r * 192 + j] * w;
    }
    if (half == 1) {
#pragma unroll
        for (int r = 0; r < 4; ++r) pu[r * 96 + h] = d[r];
    }
    __syncthreads();
    if (half == 0) {
        float bo = bout[h];
#pragma unroll
        for (int r = 0; r < 4; ++r) {
            int nn = n0 + r;
            if (nn < N) sL[(size_t)nn * 96 + h] = row[r * 96 + h] + bo + d[r] + pu[r * 96 + h];
        }
    }
}

__global__ __launch_bounds__(192) void head2_kernel(const float* __restrict__ sL,
        const float* __restrict__ W1, const float* __restrict__ b1,
        const float* __restrict__ W2, const float* __restrict__ b2,
        float* __restrict__ out, int N) {
    __shared__ float buf[16 * 96];
    int t = threadIdx.x, half = t / 96, h = t - half * 96;
    int n0 = blockIdx.x * 16;
    for (int i = t; i < 16 * 96; i += 192) {
        int r = i / 96, c = i - r * 96, nn = n0 + r;
        buf[i] = (nn < N) ? sL[(size_t)nn * 96 + c] : 0.f;
    }
    __syncthreads();
    int rbase = half * 8;
    float a[8]; float bb = b1[h];
#pragma unroll
    for (int r = 0; r < 8; ++r) a[r] = bb;
    for (int k = 0; k < 96; ++k) {
        float w = W1[k * 96 + h];
#pragma unroll
        for (int r = 0; r < 8; ++r) a[r] += buf[(rbase + r) * 96 + k] * w;
    }
    __syncthreads();
#pragma unroll
    for (int r = 0; r < 8; ++r) buf[(rbase + r) * 96 + h] = silu_f(a[r]);
    __syncthreads();
    if (t < 48) {
        int r = t / 3, c = t - r * 3;
        float o = b2[c];
        for (int j = 0; j < 96; ++j) o += buf[r * 96 + j] * W2[j * 3 + c];
        int nn = n0 + r;
        if (nn < N) out[nn * 3 + c] = o;
    }
}

static inline int cdiv(int a, int b) { return (a + b - 1) / b; }

extern "C" void kernel_launch(void* const* d_in, const int* in_sizes, int n_in,
                              void* d_out, int out_size, void* d_ws, size_t ws_size,
                              hipStream_t stream) {
    const float* x_L   = (const float*)d_in[0];
    const float* pos_L = (const float*)d_in[1];
    const float* x_P   = (const float*)d_in[2];
    const float* pos_P = (const float*)d_in[3];
    const int* edge_L = (const int*)d_in[4];
    const int* edge_P = (const int*)d_in[5];
    const int* csrc   = (const int*)d_in[6];
    const int* ctgt   = (const int*)d_in[7];
    const float *Wemb_L = (const float*)d_in[8],  *bemb_L = (const float*)d_in[9];
    const float *Wl_L = (const float*)d_in[10], *bl_L = (const float*)d_in[11];
    const float *Wr_L = (const float*)d_in[12], *br_L = (const float*)d_in[13];
    const float *We_L = (const float*)d_in[14], *att_L = (const float*)d_in[15], *bias_L = (const float*)d_in[16];
    const float *Wemb_P = (const float*)d_in[17], *bemb_P = (const float*)d_in[18];
    const float *Wl_P = (const float*)d_in[19], *bl_P = (const float*)d_in[20];
    const float *Wr_P = (const float*)d_in[21], *br_P = (const float*)d_in[22];
    const float *We_P = (const float*)d_in[23], *att_P = (const float*)d_in[24], *bias_P = (const float*)d_in[25];
    const float *Win = (const float*)d_in[26], *b_in = (const float*)d_in[27];
    const float *Wout = (const float*)d_in[28], *bout = (const float*)d_in[29];
    const float *Wq = (const float*)d_in[30], *bq = (const float*)d_in[31];
    const float *Wk = (const float*)d_in[32], *bk = (const float*)d_in[33];
    const float *Wv = (const float*)d_in[34], *bv = (const float*)d_in[35];
    const float *W1 = (const float*)d_in[36], *b1 = (const float*)d_in[37];
    const float *W2 = (const float*)d_in[38], *b2 = (const float*)d_in[39];

    const int N_L = in_sizes[1] / 3;
    const int N_P = in_sizes[3] / 3;
    const int E_L = in_sizes[4] / 2;
    const int E_P = in_sizes[5] / 2;
    const int E_X = in_sizes[6];
    const int D_L = in_sizes[0] / N_L;
    const int D_P = in_sizes[2] / N_P;
    const int Emax = (E_L > E_P ? E_L : E_P);
    const int Nmax = N_L > N_P ? N_L : N_P;

    // workspace layout (4B units)
    float* ws     = (float*)d_ws;
    float* s_L    = ws;                                  // N_L*96
    float* s_P    = s_L + (size_t)N_L * 96;              // N_P*96
    float* xl     = s_P + (size_t)N_P * 96;              // N_P*96 (later qn)
    float* xr     = xl + (size_t)N_P * 96;               // N_P*96 (later kn)
    float* vn     = xr + (size_t)N_P * 96;               // N_P*96
    int2*  sd     = (int2*)(vn + (size_t)N_P * 96);      // Emax int2 (L then P, reused)
    int*   csrc_s = (int*)sd + 2 * (size_t)Emax;         // E_X ints
    float* clog_s = (float*)(csrc_s + (size_t)E_X);      // E_X floats
    float* T_L    = clog_s + (size_t)E_X;                // 1025*96
    float* T_P    = T_L + 1025 * 96;                     // 1025*96
    int*   rowptr = (int*)(T_P + 1025 * 96);             // Nmax+1
    int*   count  = rowptr + (size_t)Nmax + 1;           // Nmax
    int*   cursor = count + (size_t)Nmax;                // Nmax
    float* csc    = (float*)(cursor + (size_t)Nmax);     // 2
    int*   bsum   = (int*)(csc + 2);                     // up to 16

    // RBF@We lookup tables (independent of everything else)
    rbf_table_kernel<<<2050, 96, 0, stream>>>(We_L, We_P, T_L, T_P);

    // ---------------- L encoder ----------------
    embed2_kernel<<<cdiv(N_L, 16), 192, 0, stream>>>(x_L, Wemb_L, bemb_L, s_L, N_L, D_L);
    lin2_kernel<<<cdiv(N_L, 16), 192, 0, stream>>>(s_L, Wl_L, bl_L, Wr_L, br_L, xl, xr, N_L);
    fill_i<<<cdiv(N_L, 256), 256, 0, stream>>>(count, 0, N_L);
    hist_kernel<<<cdiv(E_L, 256), 256, 0, stream>>>(edge_L + E_L, count, E_L);
    scan_blocksum_kernel<<<cdiv(N_L, 4096), 256, 0, stream>>>(count, bsum, N_L);
    scan_top_kernel<<<1, 64, 0, stream>>>(bsum, cdiv(N_L, 4096));
    scan_apply_kernel<<<cdiv(N_L, 4096), 256, 0, stream>>>(count, bsum, rowptr, cursor, N_L, E_L);
    gat_pre_kernel<<<cdiv(E_L, 256), 256, 0, stream>>>(edge_L, edge_L + E_L, pos_L, cursor, sd, E_L);
    gat_v3_kernel<<<cdiv(N_L, 8), 256, 0, stream>>>(rowptr, sd, xl, xr, T_L, att_L, bias_L, s_L, N_L);

    // ---------------- P encoder ----------------
    embed2_kernel<<<cdiv(N_P, 16), 192, 0, stream>>>(x_P, Wemb_P, bemb_P, s_P, N_P, D_P);
    lin2_kernel<<<cdiv(N_P, 16), 192, 0, stream>>>(s_P, Wl_P, bl_P, Wr_P, br_P, xl, xr, N_P);
    fill_i<<<cdiv(N_P, 256), 256, 0, stream>>>(count, 0, N_P);
    hist_kernel<<<cdiv(E_P, 256), 256, 0, stream>>>(edge_P + E_P, count, E_P);
    scan_blocksum_kernel<<<cdiv(N_P, 4096), 256, 0, stream>>>(count, bsum, N_P);
    scan_top_kernel<<<1, 64, 0, stream>>>(bsum, cdiv(N_P, 4096));
    scan_apply_kernel<<<cdiv(N_P, 4096), 256, 0, stream>>>(count, bsum, rowptr, cursor, N_P, E_P);
    gat_pre_kernel<<<cdiv(E_P, 256), 256, 0, stream>>>(edge_P, edge_P + E_P, pos_P, cursor, sd, E_P);
    gat_v3_kernel<<<cdiv(N_P, 8), 256, 0, stream>>>(rowptr, sd, xl, xr, T_P, att_P, bias_P, s_P, N_P);

    // ---------------- SSM block (L) ----------------
    ssm2_kernel<<<cdiv(N_L, 4), 192, 0, stream>>>(s_L, Win, b_in, Wout, bout, N_L);

    // ---------------- cross attention ----------------
    lin2_kernel<<<cdiv(N_L, 16), 192, 0, stream>>>(s_L, Wq, bq, nullptr, nullptr, xl, nullptr, N_L);
    lin2_kernel<<<cdiv(N_P, 16), 192, 0, stream>>>(s_P, Wk, bk, Wv, bv, xr, vn, N_P);
    fill_i<<<cdiv(N_L, 256), 256, 0, stream>>>(count, 0, N_L);
    hist_kernel<<<cdiv(E_X, 256), 256, 0, stream>>>(ctgt, count, E_X);
    scan_blocksum_kernel<<<cdiv(N_L, 4096), 256, 0, stream>>>(count, bsum, N_L);
    scan_top_kernel<<<1, 64, 0, stream>>>(bsum, cdiv(N_L, 4096));
    scan_apply_kernel<<<cdiv(N_L, 4096), 256, 0, stream>>>(count, bsum, rowptr, cursor, N_L, E_X);
    cross_pre_kernel<<<cdiv(E_X, 256), 256, 0, stream>>>(csrc, ctgt, cursor, csrc_s, E_X);
    init_csc<<<1, 64, 0, stream>>>(csc);
    cross_logit_v3_kernel<<<cdiv(N_L, 8), 256, 0, stream>>>(rowptr, csrc_s, xl, xr, clog_s, csc, N_L);
    cross_denom_kernel<<<cdiv(E_X, 256), 256, 0, stream>>>(clog_s, csc, E_X);
    cross_apply_v3_kernel<<<cdiv(N_L, 8), 256, 0, stream>>>(rowptr, csrc_s, clog_s, vn, csc, s_L, N_L);

    // ---------------- head ----------------
    head2_kernel<<<cdiv(N_L, 16), 192, 0, stream>>>(s_L, W1, b1, W2, b2, (float*)d_out, N_L);
}

// Round 8
// 588.291 us; speedup vs baseline: 1.6793x; 1.2522x over previous
//
#include <hip/hip_runtime.h>

__device__ __forceinline__ float silu_f(float x) { return x / (1.f + __expf(-x)); }

__device__ __forceinline__ void atomicMaxF(float* addr, float val) {
    if (val >= 0.f) atomicMax((int*)addr, __float_as_int(val));
    else            atomicMin((unsigned int*)addr, __float_as_uint(val));
}

// f32 -> bf16 (RNE) and back
__device__ __forceinline__ unsigned short f2bf(float x) {
    unsigned int u = __float_as_uint(x);
    return (unsigned short)((u + 0x7fffu + ((u >> 16) & 1u)) >> 16);
}
__device__ __forceinline__ float bf2f(unsigned short h) {
    return __uint_as_float(((unsigned int)h) << 16);
}
__device__ __forceinline__ float bf_lo(unsigned int u) { return __uint_as_float(u << 16); }
__device__ __forceinline__ float bf_hi(unsigned int u) { return __uint_as_float(u & 0xffff0000u); }
__device__ __forceinline__ float bfdot(unsigned int a, unsigned int b) {
    return bf_lo(a) * bf_lo(b) + bf_hi(a) * bf_hi(b);
}

__global__ void fill_i(int* __restrict__ p, int v, int n) {
    int i = blockIdx.x * blockDim.x + threadIdx.x;
    if (i < n) p[i] = v;
}

// combined histogram over [L | P | X] target-node space
__global__ __launch_bounds__(256) void hist_all_kernel(const int* __restrict__ tgtL,
        const int* __restrict__ tgtP, const int* __restrict__ ctgt, int* __restrict__ count,
        int E_L, int E_P, int E_X, int N_L, int N_P) {
    int e = blockIdx.x * blockDim.x + threadIdx.x;
    if (e < E_L) atomicAdd(&count[tgtL[e]], 1);
    else if (e < E_L + E_P) atomicAdd(&count[N_L + tgtP[e - E_L]], 1);
    else if (e < E_L + E_P + E_X) atomicAdd(&count[N_L + N_P + ctgt[e - E_L - E_P]], 1);
}

// ---- hierarchical scan ----
__global__ __launch_bounds__(256) void scan_blocksum_kernel(const int* __restrict__ count,
                                                            int* __restrict__ bsum, int n) {
    int b = blockIdx.x, t = threadIdx.x;
    int base = b * 4096 + t * 16;
    int s = 0;
#pragma unroll
    for (int k = 0; k < 16; ++k) {
        int idx = base + k;
        s += (idx < n) ? count[idx] : 0;
    }
#pragma unroll
    for (int off = 1; off < 64; off <<= 1) s += __shfl_xor(s, off, 64);
    __shared__ int ws[4];
    int lane = t & 63, wid = t >> 6;
    if (lane == 0) ws[wid] = s;
    __syncthreads();
    if (t == 0) bsum[b] = ws[0] + ws[1] + ws[2] + ws[3];
}

__global__ void scan_top_kernel(int* __restrict__ bsum, int nb, float* __restrict__ csc) {
    if (threadIdx.x == 0) {
        int run = 0;
        for (int i = 0; i < nb; ++i) { int c = bsum[i]; bsum[i] = run; run += c; }
        csc[0] = -3.4e38f; csc[1] = 0.f;
    }
}

__global__ __launch_bounds__(256) void scan_apply_kernel(const int* __restrict__ count,
        const int* __restrict__ bsum, int* __restrict__ rowptr, int* __restrict__ cursor,
        int n, int E) {
    int b = blockIdx.x, t = threadIdx.x;
    int base = b * 4096 + t * 16;
    int v[16];
    int s = 0;
#pragma unroll
    for (int k = 0; k < 16; ++k) {
        int idx = base + k;
        v[k] = (idx < n) ? count[idx] : 0;
        s += v[k];
    }
    int lane = t & 63, wid = t >> 6;
    int inc = s;
#pragma unroll
    for (int off = 1; off < 64; off <<= 1) {
        int o = __shfl_up(inc, off, 64);
        if (lane >= off) inc += o;
    }
    __shared__ int ws[4];
    if (lane == 63) ws[wid] = inc;
    __syncthreads();
    int woff = 0;
    for (int w = 0; w < wid; ++w) woff += ws[w];
    int prefix = bsum[b] + woff + (inc - s);
#pragma unroll
    for (int k = 0; k < 16; ++k) {
        int idx = base + k;
        if (idx < n) { rowptr[idx] = prefix; cursor[idx] = prefix; prefix += v[k]; }
    }
    if (b == 0 && t == 0) rowptr[n] = E;
}

// combined CSR fill: L/P edges -> (src, dist); X edges -> (src, tgt)
__global__ __launch_bounds__(256) void pre_all_kernel(const int* __restrict__ eL,
        const int* __restrict__ eP, const int* __restrict__ csrc, const int* __restrict__ ctgt,
        const float* __restrict__ posL, const float* __restrict__ posP,
        int* __restrict__ cursor, int2* __restrict__ sd,
        int E_L, int E_P, int E_X, int N_L, int N_P) {
    int e = blockIdx.x * blockDim.x + threadIdx.x;
    if (e >= E_L + E_P + E_X) return;
    int si, node, aux;
    if (e < E_L + E_P) {
        const int* ed; const float* pos; int idx;
        if (e < E_L) { ed = eL; pos = posL; idx = e; node = 0; }
        else         { ed = eP; pos = posP; idx = e - E_L; node = N_L; }
        int E = (e < E_L) ? E_L : E_P;
        si = ed[idx]; int ti = ed[E + idx];
        node += ti;
        float dx = pos[si * 3 + 0] - pos[ti * 3 + 0];
        float dy = pos[si * 3 + 1] - pos[ti * 3 + 1];
        float dz = pos[si * 3 + 2] - pos[ti * 3 + 2];
        aux = __float_as_int(sqrtf(dx * dx + dy * dy + dz * dz));
    } else {
        int idx = e - E_L - E_P;
        si = csrc[idx];
        aux = ctgt[idx];
        node = N_L + N_P + aux;
    }
    int p = atomicAdd(&cursor[node], 1);
    sd[p] = make_int2(si, aux);
}

// packed RBF@We table: T2[i][h] = bf16(T(i/64)) | bf16(T((i+1)/64)-T(i/64))<<16, i in [0,1024)
__global__ __launch_bounds__(96) void rbf_table_pack_kernel(const float* __restrict__ We_L,
        const float* __restrict__ We_P, unsigned int* __restrict__ T2_L,
        unsigned int* __restrict__ T2_P) {
    int b = blockIdx.x;
    const float* We = (b < 1024) ? We_L : We_P;
    unsigned int* T2 = (b < 1024) ? T2_L : T2_P;
    int i = (b < 1024) ? b : b - 1024;
    int h = threadIdx.x;
    float d0 = (float)i * 0.015625f, d1 = (float)(i + 1) * 0.015625f;
    float a0 = 0.f, a1 = 0.f;
#pragma unroll
    for (int g = 0; g < 16; ++g) {
        float w = We[g * 96 + h];
        float t0 = d0 - 0.66666667f * (float)g;
        float t1 = d1 - 0.66666667f * (float)g;
        a0 += __expf(-1.125f * t0 * t0) * w;
        a1 += __expf(-1.125f * t1 * t1) * w;
    }
    T2[i * 96 + h] = (unsigned int)f2bf(a0) | ((unsigned int)f2bf(a1 - a0) << 16);
}

// GATv2 v4: half-wave per node; bf16 xl gather + packed bf16 table; unroll-4 prefetch.
__global__ __launch_bounds__(256) void gat_v4_kernel(const int* __restrict__ rowptr,
        const int2* __restrict__ sd, const unsigned short* __restrict__ xlb,
        const float* __restrict__ xr, const unsigned int* __restrict__ T2,
        const float* __restrict__ att, const float* __restrict__ bias,
        float* __restrict__ s, int N) {
    int tid = threadIdx.x;
    int l = tid & 31;
    int n = blockIdx.x * 8 + (tid >> 5);
    if (n >= N) return;
    float att0 = att[l], att1 = att[32 + l], att2 = att[64 + l];
    size_t nb = (size_t)n * 96;
    float xr0 = xr[nb + l], xr1 = xr[nb + 32 + l], xr2 = xr[nb + 64 + l];
    int beg = rowptr[n], end = rowptr[n + 1];
    float m = -3.4e38f, d = 0.f, a0 = 0.f, a1 = 0.f, a2 = 0.f;
    for (int j = beg; j < end; j += 4) {
        unsigned int tp0[4], tp1[4], tp2[4];
        unsigned short xs0[4], xs1[4], xs2[4];
        float ff[4];
#pragma unroll
        for (int k = 0; k < 4; ++k) {
            int jj = min(j + k, end - 1);
            int2 e = sd[jj];
            float dist = __int_as_float(e.y);
            float dt = fminf(dist * 64.f, 1023.f);
            int i = (int)dt;
            ff[k] = dt - (float)i;
            const unsigned int* tr = T2 + (size_t)i * 96;
            tp0[k] = tr[l]; tp1[k] = tr[32 + l]; tp2[k] = tr[64 + l];
            const unsigned short* xp = xlb + (size_t)e.x * 96;
            xs0[k] = xp[l]; xs1[k] = xp[32 + l]; xs2[k] = xp[64 + l];
        }
        float y0[4], y1[4], y2[4], lt[4];
#pragma unroll
        for (int k = 0; k < 4; ++k) {
            y0[k] = bf2f(xs0[k]); y1[k] = bf2f(xs1[k]); y2[k] = bf2f(xs2[k]);
            float v0 = y0[k] + xr0 + bf_lo(tp0[k]) + ff[k] * bf_hi(tp0[k]);
            float v1 = y1[k] + xr1 + bf_lo(tp1[k]) + ff[k] * bf_hi(tp1[k]);
            float v2 = y2[k] + xr2 + bf_lo(tp2[k]) + ff[k] * bf_hi(tp2[k]);
            v0 = fmaxf(v0, 0.f) + 0.2f * fminf(v0, 0.f);
            v1 = fmaxf(v1, 0.f) + 0.2f * fminf(v1, 0.f);
            v2 = fmaxf(v2, 0.f) + 0.2f * fminf(v2, 0.f);
            float t = v0 * att0 + v1 * att1 + v2 * att2;
#pragma unroll
            for (int off = 1; off < 32; off <<= 1) t += __shfl_xor(t, off, 64);
            lt[k] = (j + k < end) ? t : -3.4e38f;
        }
        float bm = fmaxf(fmaxf(lt[0], lt[1]), fmaxf(lt[2], lt[3]));
        float nm = fmaxf(m, bm);
        float sc = __expf(m - nm);
        d *= sc; a0 *= sc; a1 *= sc; a2 *= sc;
#pragma unroll
        for (int k = 0; k < 4; ++k) {
            float w = __expf(lt[k] - nm);
            d += w;
            a0 += w * y0[k]; a1 += w * y1[k]; a2 += w * y2[k];
        }
        m = nm;
    }
    float agg0 = (d > 0.f) ? a0 / d : 0.f;
    float agg1 = (d > 0.f) ? a1 / d : 0.f;
    float agg2 = (d > 0.f) ? a2 / d : 0.f;
    s[nb + l]      += silu_f(agg0 + bias[l]);
    s[nb + 32 + l] += silu_f(agg1 + bias[32 + l]);
    s[nb + 64 + l] += silu_f(agg2 + bias[64 + l]);
}

// edge-parallel cross logits over CSR slots (sd.y = tgt); bf16 q,k rows via uint4 loads
__global__ __launch_bounds__(256) void cross_logit_e_kernel(const int2* __restrict__ sdX,
        const unsigned short* __restrict__ qnb, const unsigned short* __restrict__ knb,
        float* __restrict__ clog_s, float* __restrict__ csc, int E) {
    int e = blockIdx.x * blockDim.x + threadIdx.x;
    float logit = -3.4e38f;
    if (e < E) {
        int2 st = sdX[e];
        const uint4* q4 = (const uint4*)(qnb + (size_t)st.y * 96);
        const uint4* k4 = (const uint4*)(knb + (size_t)st.x * 96);
        float acc = 0.f;
#pragma unroll
        for (int i = 0; i < 12; ++i) {
            uint4 qa = q4[i], ka = k4[i];
            acc += bfdot(qa.x, ka.x) + bfdot(qa.y, ka.y) + bfdot(qa.z, ka.z) + bfdot(qa.w, ka.w);
        }
        logit = acc * 0.125f;
        clog_s[e] = logit;
    }
    __shared__ float red[256];
    red[threadIdx.x] = logit; __syncthreads();
    for (int s = 128; s > 0; s >>= 1) {
        if (threadIdx.x < s) red[threadIdx.x] = fmaxf(red[threadIdx.x], red[threadIdx.x + s]);
        __syncthreads();
    }
    if (threadIdx.x == 0) atomicMaxF(&csc[0], red[0]);
}

__global__ __launch_bounds__(256) void cross_denom_kernel(const float* __restrict__ clog_s,
                                                          float* __restrict__ csc, int E) {
    int e = blockIdx.x * blockDim.x + threadIdx.x;
    float a = 0.f;
    float mg = csc[0];
    if (e < E) a = __expf(clog_s[e] - mg);
    __shared__ float red[256];
    red[threadIdx.x] = a; __syncthreads();
    for (int s = 128; s > 0; s >>= 1) {
        if (threadIdx.x < s) red[threadIdx.x] += red[threadIdx.x + s];
        __syncthreads();
    }
    if (threadIdx.x == 0) atomicAdd(&csc[1], red[0]);
}

// cross apply v4: half-wave per node, bf16 vn gather, unroll-4
// rowptr/sd are absolute; clogA is clog_s pre-offset so clogA[absolute j] is valid.
__global__ __launch_bounds__(256) void cross_apply_v4_kernel(const int* __restrict__ rowptr,
        const int2* __restrict__ sd, const float* __restrict__ clogA,
        const unsigned short* __restrict__ vnb, const float* __restrict__ csc,
        float* __restrict__ sL, int N) {
    int tid = threadIdx.x;
    int l = tid & 31;
    int n = blockIdx.x * 8 + (tid >> 5);
    if (n >= N) return;
    int beg = rowptr[n], end = rowptr[n + 1];
    if (beg == end) return;
    float M = csc[0], invD = 1.f / csc[1];
    float a0 = 0.f, a1 = 0.f, a2 = 0.f;
    for (int j = beg; j < end; j += 4) {
        unsigned short v0[4], v1[4], v2[4]; float w[4];
#pragma unroll
        for (int k = 0; k < 4; ++k) {
            int jj = min(j + k, end - 1);
            const unsigned short* vp = vnb + (size_t)sd[jj].x * 96;
            v0[k] = vp[l]; v1[k] = vp[32 + l]; v2[k] = vp[64 + l];
            w[k] = (j + k < end) ? __expf(clogA[jj] - M) : 0.f;
        }
#pragma unroll
        for (int k = 0; k < 4; ++k) {
            a0 += w[k] * bf2f(v0[k]); a1 += w[k] * bf2f(v1[k]); a2 += w[k] * bf2f(v2[k]);
        }
    }
    size_t nb = (size_t)n * 96;
    sL[nb + l]      += a0 * invD;
    sL[nb + 32 + l] += a1 * invD;
    sL[nb + 64 + l] += a2 * invD;
}

// ---------- row-blocked dense kernels ----------

__global__ __launch_bounds__(192) void embed2_kernel(const float* __restrict__ x,
        const float* __restrict__ W, const float* __restrict__ b,
        float* __restrict__ s, int N, int D) {
    __shared__ float xs[16 * 167];
    int t = threadIdx.x, half = t / 96, h = t - half * 96;
    int n0 = blockIdx.x * 16;
    for (int i = t; i < 16 * D; i += 192) {
        int r = i / D, dd = i - r * D, nn = n0 + r;
        xs[i] = (nn < N) ? x[(size_t)nn * D + dd] : 0.f;
    }
    __syncthreads();
    float acc[8]; float bb = b[h];
#pragma unroll
    for (int r = 0; r < 8; ++r) acc[r] = bb;
    const float* xp = &xs[half * 8 * D];
    for (int dd = 0; dd < D; ++dd) {
        float w = W[dd * 96 + h];
#pragma unroll
        for (int r = 0; r < 8; ++r) acc[r] += xp[r * D + dd] * w;
    }
#pragma unroll
    for (int r = 0; r < 8; ++r) {
        int nn = n0 + half * 8 + r;
        if (nn < N) s[(size_t)nn * 96 + h] = silu_f(acc[r]);
    }
}

// one or two HxH linears; o1 always bf16; second output either f32 (o2f) or bf16 (o2b)
__global__ __launch_bounds__(192) void lin2b_kernel(const float* __restrict__ s,
        const float* __restrict__ W1, const float* __restrict__ b1,
        const float* __restrict__ W2, const float* __restrict__ b2,
        unsigned short* __restrict__ o1b, unsigned short* __restrict__ o2b,
        float* __restrict__ o2f, int N) {
    __shared__ float xs[16 * 96];
    int t = threadIdx.x, half = t / 96, h = t - half * 96;
    int n0 = blockIdx.x * 16;
    for (int i = t; i < 16 * 96; i += 192) {
        int r = i / 96, c = i - r * 96, nn = n0 + r;
        xs[i] = (nn < N) ? s[(size_t)nn * 96 + c] : 0.f;
    }
    __syncthreads();
    const float* xp = &xs[half * 8 * 96];
    float a1[8], a2[8];
    float bb1 = b1[h];
#pragma unroll
    for (int r = 0; r < 8; ++r) a1[r] = bb1;
    if (W2) {
        float bb2 = b2[h];
#pragma unroll
        for (int r = 0; r < 8; ++r) a2[r] = bb2;
        for (int k = 0; k < 96; ++k) {
            float w1 = W1[k * 96 + h], w2 = W2[k * 96 + h];
#pragma unroll
            for (int r = 0; r < 8; ++r) { float v = xp[r * 96 + k]; a1[r] += v * w1; a2[r] += v * w2; }
        }
#pragma unroll
        for (int r = 0; r < 8; ++r) {
            int nn = n0 + half * 8 + r;
            if (nn < N) {
                o1b[(size_t)nn * 96 + h] = f2bf(a1[r]);
                if (o2f) o2f[(size_t)nn * 96 + h] = a2[r];
                else     o2b[(size_t)nn * 96 + h] = f2bf(a2[r]);
            }
        }
    } else {
        for (int k = 0; k < 96; ++k) {
            float w1 = W1[k * 96 + h];
#pragma unroll
            for (int r = 0; r < 8; ++r) a1[r] += xp[r * 96 + k] * w1;
        }
#pragma unroll
        for (int r = 0; r < 8; ++r) {
            int nn = n0 + half * 8 + r;
            if (nn < N) o1b[(size_t)nn * 96 + h] = f2bf(a1[r]);
        }
    }
}

__global__ __launch_bounds__(192) void ssm2_kernel(float* __restrict__ sL,
        const float* __restrict__ Win, const float* __restrict__ b_in,
        const float* __restrict__ Wout, const float* __restrict__ bout, int N) {
    __shared__ float row[4 * 96];
    __shared__ float u[4 * 192];
    __shared__ float pu[4 * 96];
    int t = threadIdx.x;
    int n0 = blockIdx.x * 4;
    for (int i = t; i < 4 * 96; i += 192) {
        int r = i / 96, c = i - r * 96, nn = n0 + r;
        row[i] = (nn < N) ? sL[(size_t)nn * 96 + c] : 0.f;
    }
    __syncthreads();
    float acc[4]; float bb = b_in[t];
#pragma unroll
    for (int r = 0; r < 4; ++r) acc[r] = bb;
    for (int k = 0; k < 96; ++k) {
        float w = Win[k * 384 + t];
#pragma unroll
        for (int r = 0; r < 4; ++r) acc[r] += row[r * 96 + k] * w;
    }
#pragma unroll
    for (int r = 0; r < 4; ++r) u[r * 192 + t] = silu_f(acc[r]);
    __syncthreads();
    int half = t / 96, h = t - half * 96;
    float d[4] = {0.f, 0.f, 0.f, 0.f};
    int j0 = half * 96;
    for (int j = j0; j < j0 + 96; ++j) {
        float w = Wout[j * 96 + h];
#pragma unroll
        for (int r = 0; r < 4; ++r) d[r] += u[r * 192 + j] * w;
    }
    if (half == 1) {
#pragma unroll
        for (int r = 0; r < 4; ++r) pu[r * 96 + h] = d[r];
    }
    __syncthreads();
    if (half == 0) {
        float bo = bout[h];
#pragma unroll
        for (int r = 0; r < 4; ++r) {
            int nn = n0 + r;
            if (nn < N) sL[(size_t)nn * 96 + h] = row[r * 96 + h] + bo + d[r] + pu[r * 96 + h];
        }
    }
}

__global__ __launch_bounds__(192) void head2_kernel(const float* __restrict__ sL,
        const float* __restrict__ W1, const float* __restrict__ b1,
        const float* __restrict__ W2, const float* __restrict__ b2,
        float* __restrict__ out, int N) {
    __shared__ float buf[16 * 96];
    int t = threadIdx.x, half = t / 96, h = t - half * 96;
    int n0 = blockIdx.x * 16;
    for (int i = t; i < 16 * 96; i += 192) {
        int r = i / 96, c = i - r * 96, nn = n0 + r;
        buf[i] = (nn < N) ? sL[(size_t)nn * 96 + c] : 0.f;
    }
    __syncthreads();
    int rbase = half * 8;
    float a[8]; float bb = b1[h];
#pragma unroll
    for (int r = 0; r < 8; ++r) a[r] = bb;
    for (int k = 0; k < 96; ++k) {
        float w = W1[k * 96 + h];
#pragma unroll
        for (int r = 0; r < 8; ++r) a[r] += buf[(rbase + r) * 96 + k] * w;
    }
    __syncthreads();
#pragma unroll
    for (int r = 0; r < 8; ++r) buf[(rbase + r) * 96 + h] = silu_f(a[r]);
    __syncthreads();
    if (t < 48) {
        int r = t / 3, c = t - r * 3;
        float o = b2[c];
        for (int j = 0; j < 96; ++j) o += buf[r * 96 + j] * W2[j * 3 + c];
        int nn = n0 + r;
        if (nn < N) out[nn * 3 + c] = o;
    }
}

static inline int cdiv(int a, int b) { return (a + b - 1) / b; }

extern "C" void kernel_launch(void* const* d_in, const int* in_sizes, int n_in,
                              void* d_out, int out_size, void* d_ws, size_t ws_size,
                              hipStream_t stream) {
    const float* x_L   = (const float*)d_in[0];
    const float* pos_L = (const float*)d_in[1];
    const float* x_P   = (const float*)d_in[2];
    const float* pos_P = (const float*)d_in[3];
    const int* edge_L = (const int*)d_in[4];
    const int* edge_P = (const int*)d_in[5];
    const int* csrc   = (const int*)d_in[6];
    const int* ctgt   = (const int*)d_in[7];
    const float *Wemb_L = (const float*)d_in[8],  *bemb_L = (const float*)d_in[9];
    const float *Wl_L = (const float*)d_in[10], *bl_L = (const float*)d_in[11];
    const float *Wr_L = (const float*)d_in[12], *br_L = (const float*)d_in[13];
    const float *We_L = (const float*)d_in[14], *att_L = (const float*)d_in[15], *bias_L = (const float*)d_in[16];
    const float *Wemb_P = (const float*)d_in[17], *bemb_P = (const float*)d_in[18];
    const float *Wl_P = (const float*)d_in[19], *bl_P = (const float*)d_in[20];
    const float *Wr_P = (const float*)d_in[21], *br_P = (const float*)d_in[22];
    const float *We_P = (const float*)d_in[23], *att_P = (const float*)d_in[24], *bias_P = (const float*)d_in[25];
    const float *Win = (const float*)d_in[26], *b_in = (const float*)d_in[27];
    const float *Wout = (const float*)d_in[28], *bout = (const float*)d_in[29];
    const float *Wq = (const float*)d_in[30], *bq = (const float*)d_in[31];
    const float *Wk = (const float*)d_in[32], *bk = (const float*)d_in[33];
    const float *Wv = (const float*)d_in[34], *bv = (const float*)d_in[35];
    const float *W1 = (const float*)d_in[36], *b1 = (const float*)d_in[37];
    const float *W2 = (const float*)d_in[38], *b2 = (const float*)d_in[39];

    const int N_L = in_sizes[1] / 3;
    const int N_P = in_sizes[3] / 3;
    const int E_L = in_sizes[4] / 2;
    const int E_P = in_sizes[5] / 2;
    const int E_X = in_sizes[6];
    const int D_L = in_sizes[0] / N_L;
    const int D_P = in_sizes[2] / N_P;
    const int Ntot = N_L + N_P + N_L;
    const int Etot = E_L + E_P + E_X;

    // workspace layout (4-byte words; all region sizes divisible by 4 words -> 16B aligned)
    float* ws = (float*)d_ws;
    float*          s_L    = ws;                                    // N_L*96 f32
    float*          s_P    = s_L + (size_t)N_L * 96;                // N_P*96 f32
    float*          xr     = s_P + (size_t)N_P * 96;                // N_P*96 f32
    unsigned short* xlb    = (unsigned short*)(xr + (size_t)N_P * 96);   // N_P*96 bf16
    unsigned short* knb    = xlb + (size_t)N_P * 96;                // N_P*96 bf16
    unsigned short* vnb    = knb + (size_t)N_P * 96;                // N_P*96 bf16
    unsigned short* qnb    = vnb + (size_t)N_P * 96;                // N_L*96 bf16
    int2*           sdAll  = (int2*)(qnb + (size_t)N_L * 96);       // Etot int2
    float*          clog_s = (float*)(sdAll + (size_t)Etot);        // E_X f32
    unsigned int*   T2_L   = (unsigned int*)(clog_s + (size_t)E_X); // 1024*96
    unsigned int*   T2_P   = T2_L + 1024 * 96;                      // 1024*96
    int*            rowptr = (int*)(T2_P + 1024 * 96);              // Ntot+1
    int*            count  = rowptr + (size_t)Ntot + 1;             // Ntot
    int*            cursor = count + (size_t)Ntot;                  // Ntot
    float*          csc    = (float*)(cursor + (size_t)Ntot);       // 2
    int*            bsum   = (int*)(csc + 2);                       // <=16

    const int baseX = E_L + E_P;

    // tables + combined CSR build
    rbf_table_pack_kernel<<<2048, 96, 0, stream>>>(We_L, We_P, T2_L, T2_P);
    fill_i<<<cdiv(Ntot, 256), 256, 0, stream>>>(count, 0, Ntot);
    hist_all_kernel<<<cdiv(Etot, 256), 256, 0, stream>>>(edge_L + E_L, edge_P + E_P, ctgt,
        count, E_L, E_P, E_X, N_L, N_P);
    scan_blocksum_kernel<<<cdiv(Ntot, 4096), 256, 0, stream>>>(count, bsum, Ntot);
    scan_top_kernel<<<1, 64, 0, stream>>>(bsum, cdiv(Ntot, 4096), csc);
    scan_apply_kernel<<<cdiv(Ntot, 4096), 256, 0, stream>>>(count, bsum, rowptr, cursor, Ntot, Etot);
    pre_all_kernel<<<cdiv(Etot, 256), 256, 0, stream>>>(edge_L, edge_P, csrc, ctgt,
        pos_L, pos_P, cursor, sdAll, E_L, E_P, E_X, N_L, N_P);

    // ---------------- L encoder ----------------
    embed2_kernel<<<cdiv(N_L, 16), 192, 0, stream>>>(x_L, Wemb_L, bemb_L, s_L, N_L, D_L);
    lin2b_kernel<<<cdiv(N_L, 16), 192, 0, stream>>>(s_L, Wl_L, bl_L, Wr_L, br_L, xlb, nullptr, xr, N_L);
    gat_v4_kernel<<<cdiv(N_L, 8), 256, 0, stream>>>(rowptr, sdAll, xlb, xr, T2_L, att_L, bias_L, s_L, N_L);

    // ---------------- P encoder ----------------
    embed2_kernel<<<cdiv(N_P, 16), 192, 0, stream>>>(x_P, Wemb_P, bemb_P, s_P, N_P, D_P);
    lin2b_kernel<<<cdiv(N_P, 16), 192, 0, stream>>>(s_P, Wl_P, bl_P, Wr_P, br_P, xlb, nullptr, xr, N_P);
    gat_v4_kernel<<<cdiv(N_P, 8), 256, 0, stream>>>(rowptr + N_L, sdAll, xlb, xr, T2_P, att_P, bias_P, s_P, N_P);

    // ---------------- SSM block (L) ----------------
    ssm2_kernel<<<cdiv(N_L, 4), 192, 0, stream>>>(s_L, Win, b_in, Wout, bout, N_L);

    // ---------------- cross attention ----------------
    lin2b_kernel<<<cdiv(N_L, 16), 192, 0, stream>>>(s_L, Wq, bq, nullptr, nullptr, qnb, nullptr, nullptr, N_L);
    lin2b_kernel<<<cdiv(N_P, 16), 192, 0, stream>>>(s_P, Wk, bk, Wv, bv, knb, vnb, nullptr, N_P);
    cross_logit_e_kernel<<<cdiv(E_X, 256), 256, 0, stream>>>(sdAll + (size_t)baseX, qnb, knb,
        clog_s, csc, E_X);
    cross_denom_kernel<<<cdiv(E_X, 256), 256, 0, stream>>>(clog_s, csc, E_X);
    cross_apply_v4_kernel<<<cdiv(N_L, 8), 256, 0, stream>>>(rowptr + N_L + N_P, sdAll,
        clog_s - (size_t)baseX, vnb, csc, s_L, N_L);

    // ---------------- head ----------------
    head2_kernel<<<cdiv(N_L, 16), 192, 0, stream>>>(s_L, W1, b1, W2, b2, (float*)d_out, N_L);
}

// Round 9
// 505.379 us; speedup vs baseline: 1.9548x; 1.1641x over previous
//
#include <hip/hip_runtime.h>

__device__ __forceinline__ float silu_f(float x) { return x / (1.f + __expf(-x)); }

__device__ __forceinline__ void atomicMaxF(float* addr, float val) {
    if (val >= 0.f) atomicMax((int*)addr, __float_as_int(val));
    else            atomicMin((unsigned int*)addr, __float_as_uint(val));
}

// f32 -> bf16 (RNE) and back
__device__ __forceinline__ unsigned short f2bf(float x) {
    unsigned int u = __float_as_uint(x);
    return (unsigned short)((u + 0x7fffu + ((u >> 16) & 1u)) >> 16);
}
__device__ __forceinline__ float bf2f(unsigned short h) {
    return __uint_as_float(((unsigned int)h) << 16);
}
__device__ __forceinline__ float bf_lo(unsigned int u) { return __uint_as_float(u << 16); }
__device__ __forceinline__ float bf_hi(unsigned int u) { return __uint_as_float(u & 0xffff0000u); }
__device__ __forceinline__ float bfdot(unsigned int a, unsigned int b) {
    return bf_lo(a) * bf_lo(b) + bf_hi(a) * bf_hi(b);
}

__global__ void fill_i(int* __restrict__ p, int v, int n) {
    int i = blockIdx.x * blockDim.x + threadIdx.x;
    if (i < n) p[i] = v;
}

// combined histogram over [L | P | X] target-node space
__global__ __launch_bounds__(256) void hist_all_kernel(const int* __restrict__ tgtL,
        const int* __restrict__ tgtP, const int* __restrict__ ctgt, int* __restrict__ count,
        int E_L, int E_P, int E_X, int N_L, int N_P) {
    int e = blockIdx.x * blockDim.x + threadIdx.x;
    if (e < E_L) atomicAdd(&count[tgtL[e]], 1);
    else if (e < E_L + E_P) atomicAdd(&count[N_L + tgtP[e - E_L]], 1);
    else if (e < E_L + E_P + E_X) atomicAdd(&count[N_L + N_P + ctgt[e - E_L - E_P]], 1);
}

// ---- hierarchical scan ----
__global__ __launch_bounds__(256) void scan_blocksum_kernel(const int* __restrict__ count,
                                                            int* __restrict__ bsum, int n) {
    int b = blockIdx.x, t = threadIdx.x;
    int base = b * 4096 + t * 16;
    int s = 0;
#pragma unroll
    for (int k = 0; k < 16; ++k) {
        int idx = base + k;
        s += (idx < n) ? count[idx] : 0;
    }
#pragma unroll
    for (int off = 1; off < 64; off <<= 1) s += __shfl_xor(s, off, 64);
    __shared__ int ws[4];
    int lane = t & 63, wid = t >> 6;
    if (lane == 0) ws[wid] = s;
    __syncthreads();
    if (t == 0) bsum[b] = ws[0] + ws[1] + ws[2] + ws[3];
}

__global__ void scan_top_kernel(int* __restrict__ bsum, int nb, float* __restrict__ csc) {
    if (threadIdx.x == 0) {
        int run = 0;
        for (int i = 0; i < nb; ++i) { int c = bsum[i]; bsum[i] = run; run += c; }
        csc[0] = -3.4e38f; csc[1] = 0.f;
    }
}

__global__ __launch_bounds__(256) void scan_apply_kernel(const int* __restrict__ count,
        const int* __restrict__ bsum, int* __restrict__ rowptr, int* __restrict__ cursor,
        int n, int E) {
    int b = blockIdx.x, t = threadIdx.x;
    int base = b * 4096 + t * 16;
    int v[16];
    int s = 0;
#pragma unroll
    for (int k = 0; k < 16; ++k) {
        int idx = base + k;
        v[k] = (idx < n) ? count[idx] : 0;
        s += v[k];
    }
    int lane = t & 63, wid = t >> 6;
    int inc = s;
#pragma unroll
    for (int off = 1; off < 64; off <<= 1) {
        int o = __shfl_up(inc, off, 64);
        if (lane >= off) inc += o;
    }
    __shared__ int ws[4];
    if (lane == 63) ws[wid] = inc;
    __syncthreads();
    int woff = 0;
    for (int w = 0; w < wid; ++w) woff += ws[w];
    int prefix = bsum[b] + woff + (inc - s);
#pragma unroll
    for (int k = 0; k < 16; ++k) {
        int idx = base + k;
        if (idx < n) { rowptr[idx] = prefix; cursor[idx] = prefix; prefix += v[k]; }
    }
    if (b == 0 && t == 0) rowptr[n] = E;
}

// combined CSR fill, 4-byte packed payloads:
//  GAT edge: src_combined(16b) | distq(16b: floor(dist*4096) clamped)
//  X   edge: srcP(16b) | tgtL(16b)
__global__ __launch_bounds__(256) void pre_all_kernel(const int* __restrict__ eL,
        const int* __restrict__ eP, const int* __restrict__ csrc, const int* __restrict__ ctgt,
        const float* __restrict__ posL, const float* __restrict__ posP,
        int* __restrict__ cursor, unsigned int* __restrict__ sdp,
        int E_L, int E_P, int E_X, int N_L, int N_P) {
    int e = blockIdx.x * blockDim.x + threadIdx.x;
    if (e >= E_L + E_P + E_X) return;
    unsigned int pack;
    int node;
    if (e < E_L + E_P) {
        const int* ed; const float* pos; int idx, E, nbase;
        if (e < E_L) { ed = eL; pos = posL; idx = e; E = E_L; nbase = 0; }
        else         { ed = eP; pos = posP; idx = e - E_L; E = E_P; nbase = N_L; }
        int si = ed[idx], ti = ed[E + idx];
        node = nbase + ti;
        float dx = pos[si * 3 + 0] - pos[ti * 3 + 0];
        float dy = pos[si * 3 + 1] - pos[ti * 3 + 1];
        float dz = pos[si * 3 + 2] - pos[ti * 3 + 2];
        float dist = sqrtf(dx * dx + dy * dy + dz * dz);
        int dq = min((int)(dist * 4096.f), 65535);
        pack = (unsigned int)(si + nbase) | ((unsigned int)dq << 16);
    } else {
        int idx = e - E_L - E_P;
        int ti = ctgt[idx];
        pack = (unsigned int)csrc[idx] | ((unsigned int)ti << 16);
        node = N_L + N_P + ti;
    }
    int p = atomicAdd(&cursor[node], 1);
    sdp[p] = pack;
}

// packed RBF@We table: T2[i][h] = bf16(T(i/64)) | bf16(T((i+1)/64)-T(i/64))<<16
__global__ __launch_bounds__(96) void rbf_table_pack_kernel(const float* __restrict__ We_L,
        const float* __restrict__ We_P, unsigned int* __restrict__ T2_L,
        unsigned int* __restrict__ T2_P) {
    int b = blockIdx.x;
    const float* We = (b < 1024) ? We_L : We_P;
    unsigned int* T2 = (b < 1024) ? T2_L : T2_P;
    int i = (b < 1024) ? b : b - 1024;
    int h = threadIdx.x;
    float d0 = (float)i * 0.015625f, d1 = (float)(i + 1) * 0.015625f;
    float a0 = 0.f, a1 = 0.f;
#pragma unroll
    for (int g = 0; g < 16; ++g) {
        float w = We[g * 96 + h];
        float t0 = d0 - 0.66666667f * (float)g;
        float t1 = d1 - 0.66666667f * (float)g;
        a0 += __expf(-1.125f * t0 * t0) * w;
        a1 += __expf(-1.125f * t1 * t1) * w;
    }
    T2[i * 96 + h] = (unsigned int)f2bf(a0) | ((unsigned int)f2bf(a1 - a0) << 16);
}

// Combined L+P GATv2: half-wave per combined node n (L: [0,N_L), P: [N_L,N_L+N_P)).
__global__ __launch_bounds__(256) void gat_all_kernel(const int* __restrict__ rowptr,
        const unsigned int* __restrict__ sdp, const unsigned short* __restrict__ xlb,
        const float* __restrict__ xr,
        const unsigned int* __restrict__ T2_L, const unsigned int* __restrict__ T2_P,
        const float* __restrict__ att_L, const float* __restrict__ att_P,
        const float* __restrict__ bias_L, const float* __restrict__ bias_P,
        float* __restrict__ s_L, float* __restrict__ s_P, int N_L, int Ncomb) {
    int tid = threadIdx.x;
    int l = tid & 31;
    int n = blockIdx.x * 8 + (tid >> 5);
    if (n >= Ncomb) return;
    bool isL = n < N_L;
    const unsigned int* T2 = isL ? T2_L : T2_P;
    const float* att = isL ? att_L : att_P;
    const float* bias = isL ? bias_L : bias_P;
    float* srow = isL ? (s_L + (size_t)n * 96) : (s_P + (size_t)(n - N_L) * 96);
    float att0 = att[l], att1 = att[32 + l], att2 = att[64 + l];
    size_t nb = (size_t)n * 96;
    float xr0 = xr[nb + l], xr1 = xr[nb + 32 + l], xr2 = xr[nb + 64 + l];
    int beg = rowptr[n], end = rowptr[n + 1];
    float m = -3.4e38f, d = 0.f, a0 = 0.f, a1 = 0.f, a2 = 0.f;
    for (int j = beg; j < end; j += 4) {
        unsigned int tp0[4], tp1[4], tp2[4];
        unsigned short xs0[4], xs1[4], xs2[4];
        float ff[4];
#pragma unroll
        for (int k = 0; k < 4; ++k) {
            int jj = min(j + k, end - 1);
            unsigned int u = sdp[jj];
            int src = (int)(u & 0xffffu);
            int dq = (int)(u >> 16);
            int i = dq >> 6;
            ff[k] = (float)(dq & 63) * 0.015625f;
            const unsigned int* tr = T2 + (size_t)i * 96;
            tp0[k] = tr[l]; tp1[k] = tr[32 + l]; tp2[k] = tr[64 + l];
            const unsigned short* xp = xlb + (size_t)src * 96;
            xs0[k] = xp[l]; xs1[k] = xp[32 + l]; xs2[k] = xp[64 + l];
        }
        float y0[4], y1[4], y2[4], lt[4];
#pragma unroll
        for (int k = 0; k < 4; ++k) {
            y0[k] = bf2f(xs0[k]); y1[k] = bf2f(xs1[k]); y2[k] = bf2f(xs2[k]);
            float v0 = y0[k] + xr0 + bf_lo(tp0[k]) + ff[k] * bf_hi(tp0[k]);
            float v1 = y1[k] + xr1 + bf_lo(tp1[k]) + ff[k] * bf_hi(tp1[k]);
            float v2 = y2[k] + xr2 + bf_lo(tp2[k]) + ff[k] * bf_hi(tp2[k]);
            v0 = fmaxf(v0, 0.f) + 0.2f * fminf(v0, 0.f);
            v1 = fmaxf(v1, 0.f) + 0.2f * fminf(v1, 0.f);
            v2 = fmaxf(v2, 0.f) + 0.2f * fminf(v2, 0.f);
            float t = v0 * att0 + v1 * att1 + v2 * att2;
#pragma unroll
            for (int off = 1; off < 32; off <<= 1) t += __shfl_xor(t, off, 64);
            lt[k] = (j + k < end) ? t : -3.4e38f;
        }
        float bm = fmaxf(fmaxf(lt[0], lt[1]), fmaxf(lt[2], lt[3]));
        float nm = fmaxf(m, bm);
        float sc = __expf(m - nm);
        d *= sc; a0 *= sc; a1 *= sc; a2 *= sc;
#pragma unroll
        for (int k = 0; k < 4; ++k) {
            float w = __expf(lt[k] - nm);
            d += w;
            a0 += w * y0[k]; a1 += w * y1[k]; a2 += w * y2[k];
        }
        m = nm;
    }
    float agg0 = (d > 0.f) ? a0 / d : 0.f;
    float agg1 = (d > 0.f) ? a1 / d : 0.f;
    float agg2 = (d > 0.f) ? a2 / d : 0.f;
    srow[l]      += silu_f(agg0 + bias[l]);
    srow[32 + l] += silu_f(agg1 + bias[32 + l]);
    srow[64 + l] += silu_f(agg2 + bias[64 + l]);
}

// edge-parallel cross logits; packed slot = srcP | (tgtL<<16)
__global__ __launch_bounds__(256) void cross_logit_e_kernel(const unsigned int* __restrict__ sdX,
        const unsigned short* __restrict__ qnb, const unsigned short* __restrict__ knb,
        float* __restrict__ clog_s, float* __restrict__ csc, int E) {
    int e = blockIdx.x * blockDim.x + threadIdx.x;
    float logit = -3.4e38f;
    if (e < E) {
        unsigned int u = sdX[e];
        int src = (int)(u & 0xffffu);
        int tgt = (int)(u >> 16);
        const uint4* q4 = (const uint4*)(qnb + (size_t)tgt * 96);
        const uint4* k4 = (const uint4*)(knb + (size_t)src * 96);
        float acc = 0.f;
#pragma unroll
        for (int i = 0; i < 12; ++i) {
            uint4 qa = q4[i], ka = k4[i];
            acc += bfdot(qa.x, ka.x) + bfdot(qa.y, ka.y) + bfdot(qa.z, ka.z) + bfdot(qa.w, ka.w);
        }
        logit = acc * 0.125f;
        clog_s[e] = logit;
    }
    __shared__ float red[256];
    red[threadIdx.x] = logit; __syncthreads();
    for (int s = 128; s > 0; s >>= 1) {
        if (threadIdx.x < s) red[threadIdx.x] = fmaxf(red[threadIdx.x], red[threadIdx.x + s]);
        __syncthreads();
    }
    if (threadIdx.x == 0) atomicMaxF(&csc[0], red[0]);
}

__global__ __launch_bounds__(256) void cross_denom_kernel(const float* __restrict__ clog_s,
                                                          float* __restrict__ csc, int E) {
    int e = blockIdx.x * blockDim.x + threadIdx.x;
    float a = 0.f;
    float mg = csc[0];
    if (e < E) a = __expf(clog_s[e] - mg);
    __shared__ float red[256];
    red[threadIdx.x] = a; __syncthreads();
    for (int s = 128; s > 0; s >>= 1) {
        if (threadIdx.x < s) red[threadIdx.x] += red[threadIdx.x + s];
        __syncthreads();
    }
    if (threadIdx.x == 0) atomicAdd(&csc[1], red[0]);
}

// cross apply: half-wave per L node; absolute CSR slots; clog index = slot - baseX
__global__ __launch_bounds__(256) void cross_apply_v4_kernel(const int* __restrict__ rowptr,
        const unsigned int* __restrict__ sdp, const float* __restrict__ clog_s,
        const unsigned short* __restrict__ vnb, const float* __restrict__ csc,
        float* __restrict__ sL, int N, int baseX) {
    int tid = threadIdx.x;
    int l = tid & 31;
    int n = blockIdx.x * 8 + (tid >> 5);
    if (n >= N) return;
    int beg = rowptr[n], end = rowptr[n + 1];
    if (beg == end) return;
    float M = csc[0], invD = 1.f / csc[1];
    float a0 = 0.f, a1 = 0.f, a2 = 0.f;
    for (int j = beg; j < end; j += 4) {
        unsigned short v0[4], v1[4], v2[4]; float w[4];
#pragma unroll
        for (int k = 0; k < 4; ++k) {
            int jj = min(j + k, end - 1);
            int src = (int)(sdp[jj] & 0xffffu);
            const unsigned short* vp = vnb + (size_t)src * 96;
            v0[k] = vp[l]; v1[k] = vp[32 + l]; v2[k] = vp[64 + l];
            w[k] = (j + k < end) ? __expf(clog_s[jj - baseX] - M) : 0.f;
        }
#pragma unroll
        for (int k = 0; k < 4; ++k) {
            a0 += w[k] * bf2f(v0[k]); a1 += w[k] * bf2f(v1[k]); a2 += w[k] * bf2f(v2[k]);
        }
    }
    size_t nb = (size_t)n * 96;
    sL[nb + l]      += a0 * invD;
    sL[nb + 32 + l] += a1 * invD;
    sL[nb + 64 + l] += a2 * invD;
}

// ---------- fused dense kernels ----------

// embed + dual linear for L and P in one launch; blocks [0,BL) = L, [BL,..) = P.
// s kept in LDS between the two stages; xl -> bf16 combined array, xr -> f32 combined.
__global__ __launch_bounds__(192) void enc_all_kernel(
        const float* __restrict__ x_L, const float* __restrict__ x_P,
        const float* __restrict__ WembL, const float* __restrict__ bembL,
        const float* __restrict__ WembP, const float* __restrict__ bembP,
        const float* __restrict__ WlL, const float* __restrict__ blL,
        const float* __restrict__ WrL, const float* __restrict__ brL,
        const float* __restrict__ WlP, const float* __restrict__ blP,
        const float* __restrict__ WrP, const float* __restrict__ brP,
        float* __restrict__ s_L, float* __restrict__ s_P,
        unsigned short* __restrict__ xlb, float* __restrict__ xr,
        int N_L, int N_P, int D_L, int D_P, int BL) {
    __shared__ float xs[16 * 167];
    __shared__ float ss[16 * 96];
    int b = blockIdx.x;
    bool isL = b < BL;
    const float* x    = isL ? x_L : x_P;
    const float* Wemb = isL ? WembL : WembP;
    const float* bemb = isL ? bembL : bembP;
    const float* Wl   = isL ? WlL : WlP;
    const float* bl   = isL ? blL : blP;
    const float* Wr   = isL ? WrL : WrP;
    const float* br   = isL ? brL : brP;
    float* sOut = isL ? s_L : s_P;
    int N = isL ? N_L : N_P;
    int D = isL ? D_L : D_P;
    int n0 = (isL ? b : b - BL) * 16;
    int cbase = isL ? 0 : N_L;
    int t = threadIdx.x, half = t / 96, h = t - half * 96;
    for (int i = t; i < 16 * D; i += 192) {
        int r = i / D, dd = i - r * D, nn = n0 + r;
        xs[i] = (nn < N) ? x[(size_t)nn * D + dd] : 0.f;
    }
    __syncthreads();
    float acc[8]; float bb = bemb[h];
#pragma unroll
    for (int r = 0; r < 8; ++r) acc[r] = bb;
    const float* xp = &xs[half * 8 * D];
    for (int dd = 0; dd < D; ++dd) {
        float w = Wemb[dd * 96 + h];
#pragma unroll
        for (int r = 0; r < 8; ++r) acc[r] += xp[r * D + dd] * w;
    }
#pragma unroll
    for (int r = 0; r < 8; ++r) {
        int nn = n0 + half * 8 + r;
        float v = silu_f(acc[r]);
        if (nn < N) sOut[(size_t)nn * 96 + h] = v;
        ss[(half * 8 + r) * 96 + h] = v;
    }
    __syncthreads();
    const float* sp = &ss[half * 8 * 96];
    float a1[8], a2[8];
    float bb1 = bl[h], bb2 = br[h];
#pragma unroll
    for (int r = 0; r < 8; ++r) { a1[r] = bb1; a2[r] = bb2; }
    for (int k = 0; k < 96; ++k) {
        float w1 = Wl[k * 96 + h], w2 = Wr[k * 96 + h];
#pragma unroll
        for (int r = 0; r < 8; ++r) { float v = sp[r * 96 + k]; a1[r] += v * w1; a2[r] += v * w2; }
    }
#pragma unroll
    for (int r = 0; r < 8; ++r) {
        int nn = n0 + half * 8 + r;
        if (nn < N) {
            xlb[(size_t)(cbase + nn) * 96 + h] = f2bf(a1[r]);
            xr[(size_t)(cbase + nn) * 96 + h] = a2[r];
        }
    }
}

// q (L) and k,v (P) projections in one launch; blocks [0,BL) = L/q, rest = P/kv.
__global__ __launch_bounds__(192) void qkv_all_kernel(
        const float* __restrict__ s_L, const float* __restrict__ s_P,
        const float* __restrict__ Wq, const float* __restrict__ bq,
        const float* __restrict__ Wk, const float* __restrict__ bk,
        const float* __restrict__ Wv, const float* __restrict__ bv,
        unsigned short* __restrict__ qnb, unsigned short* __restrict__ knb,
        unsigned short* __restrict__ vnb, int N_L, int N_P, int BL) {
    __shared__ float xs[16 * 96];
    int b = blockIdx.x;
    bool isL = b < BL;
    const float* s = isL ? s_L : s_P;
    int N = isL ? N_L : N_P;
    int n0 = (isL ? b : b - BL) * 16;
    int t = threadIdx.x, half = t / 96, h = t - half * 96;
    for (int i = t; i < 16 * 96; i += 192) {
        int r = i / 96, c = i - r * 96, nn = n0 + r;
        xs[i] = (nn < N) ? s[(size_t)nn * 96 + c] : 0.f;
    }
    __syncthreads();
    const float* xp = &xs[half * 8 * 96];
    if (isL) {
        float a1[8]; float bb1 = bq[h];
#pragma unroll
        for (int r = 0; r < 8; ++r) a1[r] = bb1;
        for (int k = 0; k < 96; ++k) {
            float w1 = Wq[k * 96 + h];
#pragma unroll
            for (int r = 0; r < 8; ++r) a1[r] += xp[r * 96 + k] * w1;
        }
#pragma unroll
        for (int r = 0; r < 8; ++r) {
            int nn = n0 + half * 8 + r;
            if (nn < N) qnb[(size_t)nn * 96 + h] = f2bf(a1[r]);
        }
    } else {
        float a1[8], a2[8];
        float bb1 = bk[h], bb2 = bv[h];
#pragma unroll
        for (int r = 0; r < 8; ++r) { a1[r] = bb1; a2[r] = bb2; }
        for (int k = 0; k < 96; ++k) {
            float w1 = Wk[k * 96 + h], w2 = Wv[k * 96 + h];
#pragma unroll
            for (int r = 0; r < 8; ++r) { float v = xp[r * 96 + k]; a1[r] += v * w1; a2[r] += v * w2; }
        }
#pragma unroll
        for (int r = 0; r < 8; ++r) {
            int nn = n0 + half * 8 + r;
            if (nn < N) {
                knb[(size_t)nn * 96 + h] = f2bf(a1[r]);
                vnb[(size_t)nn * 96 + h] = f2bf(a2[r]);
            }
        }
    }
}

__global__ __launch_bounds__(192) void ssm2_kernel(float* __restrict__ sL,
        const float* __restrict__ Win, const float* __restrict__ b_in,
        const float* __restrict__ Wout, const float* __restrict__ bout, int N) {
    __shared__ float row[4 * 96];
    __shared__ float u[4 * 192];
    __shared__ float pu[4 * 96];
    int t = threadIdx.x;
    int n0 = blockIdx.x * 4;
    for (int i = t; i < 4 * 96; i += 192) {
        int r = i / 96, c = i - r * 96, nn = n0 + r;
        row[i] = (nn < N) ? sL[(size_t)nn * 96 + c] : 0.f;
    }
    __syncthreads();
    float acc[4]; float bb = b_in[t];
#pragma unroll
    for (int r = 0; r < 4; ++r) acc[r] = bb;
    for (int k = 0; k < 96; ++k) {
        float w = Win[k * 384 + t];
#pragma unroll
        for (int r = 0; r < 4; ++r) acc[r] += row[r * 96 + k] * w;
    }
#pragma unroll
    for (int r = 0; r < 4; ++r) u[r * 192 + t] = silu_f(acc[r]);
    __syncthreads();
    int half = t / 96, h = t - half * 96;
    float d[4] = {0.f, 0.f, 0.f, 0.f};
    int j0 = half * 96;
    for (int j = j0; j < j0 + 96; ++j) {
        float w = Wout[j * 96 + h];
#pragma unroll
        for (int r = 0; r < 4; ++r) d[r] += u[r * 192 + j] * w;
    }
    if (half == 1) {
#pragma unroll
        for (int r = 0; r < 4; ++r) pu[r * 96 + h] = d[r];
    }
    __syncthreads();
    if (half == 0) {
        float bo = bout[h];
#pragma unroll
        for (int r = 0; r < 4; ++r) {
            int nn = n0 + r;
            if (nn < N) sL[(size_t)nn * 96 + h] = row[r * 96 + h] + bo + d[r] + pu[r * 96 + h];
        }
    }
}

__global__ __launch_bounds__(192) void head2_kernel(const float* __restrict__ sL,
        const float* __restrict__ W1, const float* __restrict__ b1,
        const float* __restrict__ W2, const float* __restrict__ b2,
        float* __restrict__ out, int N) {
    __shared__ float buf[16 * 96];
    int t = threadIdx.x, half = t / 96, h = t - half * 96;
    int n0 = blockIdx.x * 16;
    for (int i = t; i < 16 * 96; i += 192) {
        int r = i / 96, c = i - r * 96, nn = n0 + r;
        buf[i] = (nn < N) ? sL[(size_t)nn * 96 + c] : 0.f;
    }
    __syncthreads();
    int rbase = half * 8;
    float a[8]; float bb = b1[h];
#pragma unroll
    for (int r = 0; r < 8; ++r) a[r] = bb;
    for (int k = 0; k < 96; ++k) {
        float w = W1[k * 96 + h];
#pragma unroll
        for (int r = 0; r < 8; ++r) a[r] += buf[(rbase + r) * 96 + k] * w;
    }
    __syncthreads();
#pragma unroll
    for (int r = 0; r < 8; ++r) buf[(rbase + r) * 96 + h] = silu_f(a[r]);
    __syncthreads();
    if (t < 48) {
        int r = t / 3, c = t - r * 3;
        float o = b2[c];
        for (int j = 0; j < 96; ++j) o += buf[r * 96 + j] * W2[j * 3 + c];
        int nn = n0 + r;
        if (nn < N) out[nn * 3 + c] = o;
    }
}

static inline int cdiv(int a, int b) { return (a + b - 1) / b; }

extern "C" void kernel_launch(void* const* d_in, const int* in_sizes, int n_in,
                              void* d_out, int out_size, void* d_ws, size_t ws_size,
                              hipStream_t stream) {
    const float* x_L   = (const float*)d_in[0];
    const float* pos_L = (const float*)d_in[1];
    const float* x_P   = (const float*)d_in[2];
    const float* pos_P = (const float*)d_in[3];
    const int* edge_L = (const int*)d_in[4];
    const int* edge_P = (const int*)d_in[5];
    const int* csrc   = (const int*)d_in[6];
    const int* ctgt   = (const int*)d_in[7];
    const float *Wemb_L = (const float*)d_in[8],  *bemb_L = (const float*)d_in[9];
    const float *Wl_L = (const float*)d_in[10], *bl_L = (const float*)d_in[11];
    const float *Wr_L = (const float*)d_in[12], *br_L = (const float*)d_in[13];
    const float *We_L = (const float*)d_in[14], *att_L = (const float*)d_in[15], *bias_L = (const float*)d_in[16];
    const float *Wemb_P = (const float*)d_in[17], *bemb_P = (const float*)d_in[18];
    const float *Wl_P = (const float*)d_in[19], *bl_P = (const float*)d_in[20];
    const float *Wr_P = (const float*)d_in[21], *br_P = (const float*)d_in[22];
    const float *We_P = (const float*)d_in[23], *att_P = (const float*)d_in[24], *bias_P = (const float*)d_in[25];
    const float *Win = (const float*)d_in[26], *b_in = (const float*)d_in[27];
    const float *Wout = (const float*)d_in[28], *bout = (const float*)d_in[29];
    const float *Wq = (const float*)d_in[30], *bq = (const float*)d_in[31];
    const float *Wk = (const float*)d_in[32], *bk = (const float*)d_in[33];
    const float *Wv = (const float*)d_in[34], *bv = (const float*)d_in[35];
    const float *W1 = (const float*)d_in[36], *b1 = (const float*)d_in[37];
    const float *W2 = (const float*)d_in[38], *b2 = (const float*)d_in[39];

    const int N_L = in_sizes[1] / 3;
    const int N_P = in_sizes[3] / 3;
    const int E_L = in_sizes[4] / 2;
    const int E_P = in_sizes[5] / 2;
    const int E_X = in_sizes[6];
    const int D_L = in_sizes[0] / N_L;
    const int D_P = in_sizes[2] / N_P;
    const int Ncomb = N_L + N_P;
    const int Ntot = N_L + N_P + N_L;
    const int Etot = E_L + E_P + E_X;
    const int baseX = E_L + E_P;

    // workspace layout (all regions before rowptr are multiples of 16 B)
    float* ws = (float*)d_ws;
    float*          s_L    = ws;                                     // N_L*96 f32
    float*          s_P    = s_L + (size_t)N_L * 96;                 // N_P*96 f32
    float*          xr     = s_P + (size_t)N_P * 96;                 // Ncomb*96 f32
    unsigned short* xlb    = (unsigned short*)(xr + (size_t)Ncomb * 96);  // Ncomb*96 bf16
    unsigned short* knb    = xlb + (size_t)Ncomb * 96;               // N_P*96 bf16
    unsigned short* vnb    = knb + (size_t)N_P * 96;                 // N_P*96 bf16
    unsigned short* qnb    = vnb + (size_t)N_P * 96;                 // N_L*96 bf16
    unsigned int*   sdp    = (unsigned int*)(qnb + (size_t)N_L * 96);// Etot u32
    float*          clog_s = (float*)(sdp + (size_t)Etot);           // E_X f32
    unsigned int*   T2_L   = (unsigned int*)(clog_s + (size_t)E_X);  // 1024*96
    unsigned int*   T2_P   = T2_L + 1024 * 96;                       // 1024*96
    int*            rowptr = (int*)(T2_P + 1024 * 96);               // Ntot+1
    int*            count  = rowptr + (size_t)Ntot + 1;              // Ntot
    int*            cursor = count + (size_t)Ntot;                   // Ntot
    float*          csc    = (float*)(cursor + (size_t)Ntot);        // 2
    int*            bsum   = (int*)(csc + 2);                        // <=16

    const int BL = cdiv(N_L, 16), BP = cdiv(N_P, 16);

    // tables + combined CSR build
    rbf_table_pack_kernel<<<2048, 96, 0, stream>>>(We_L, We_P, T2_L, T2_P);
    fill_i<<<cdiv(Ntot, 256), 256, 0, stream>>>(count, 0, Ntot);
    hist_all_kernel<<<cdiv(Etot, 256), 256, 0, stream>>>(edge_L + E_L, edge_P + E_P, ctgt,
        count, E_L, E_P, E_X, N_L, N_P);
    scan_blocksum_kernel<<<cdiv(Ntot, 4096), 256, 0, stream>>>(count, bsum, Ntot);
    scan_top_kernel<<<1, 64, 0, stream>>>(bsum, cdiv(Ntot, 4096), csc);
    scan_apply_kernel<<<cdiv(Ntot, 4096), 256, 0, stream>>>(count, bsum, rowptr, cursor, Ntot, Etot);
    pre_all_kernel<<<cdiv(Etot, 256), 256, 0, stream>>>(edge_L, edge_P, csrc, ctgt,
        pos_L, pos_P, cursor, sdp, E_L, E_P, E_X, N_L, N_P);

    // fused embed + gat-linears for both graphs
    enc_all_kernel<<<BL + BP, 192, 0, stream>>>(x_L, x_P, Wemb_L, bemb_L, Wemb_P, bemb_P,
        Wl_L, bl_L, Wr_L, br_L, Wl_P, bl_P, Wr_P, br_P,
        s_L, s_P, xlb, xr, N_L, N_P, D_L, D_P, BL);

    // combined L+P GAT
    gat_all_kernel<<<cdiv(Ncomb, 8), 256, 0, stream>>>(rowptr, sdp, xlb, xr, T2_L, T2_P,
        att_L, att_P, bias_L, bias_P, s_L, s_P, N_L, Ncomb);

    // SSM (L)
    ssm2_kernel<<<cdiv(N_L, 4), 192, 0, stream>>>(s_L, Win, b_in, Wout, bout, N_L);

    // cross attention
    qkv_all_kernel<<<BL + BP, 192, 0, stream>>>(s_L, s_P, Wq, bq, Wk, bk, Wv, bv,
        qnb, knb, vnb, N_L, N_P, BL);
    cross_logit_e_kernel<<<cdiv(E_X, 256), 256, 0, stream>>>(sdp + (size_t)baseX, qnb, knb,
        clog_s, csc, E_X);
    cross_denom_kernel<<<cdiv(E_X, 256), 256, 0, stream>>>(clog_s, csc, E_X);
    cross_apply_v4_kernel<<<cdiv(N_L, 8), 256, 0, stream>>>(rowptr + N_L + N_P, sdp,
        clog_s, vnb, csc, s_L, N_L, baseX);

    // head
    head2_kernel<<<cdiv(N_L, 16), 192, 0, stream>>>(s_L, W1, b1, W2, b2, (float*)d_out, N_L);
}

// Round 10
// 466.497 us; speedup vs baseline: 2.1177x; 1.0833x over previous
//
#include <hip/hip_runtime.h>

__device__ __forceinline__ float silu_f(float x) { return x / (1.f + __expf(-x)); }

__device__ __forceinline__ void atomicMaxF(float* addr, float val) {
    if (val >= 0.f) atomicMax((int*)addr, __float_as_int(val));
    else            atomicMin((unsigned int*)addr, __float_as_uint(val));
}

// f32 -> bf16 (RNE) and back
__device__ __forceinline__ unsigned short f2bf(float x) {
    unsigned int u = __float_as_uint(x);
    return (unsigned short)((u + 0x7fffu + ((u >> 16) & 1u)) >> 16);
}
__device__ __forceinline__ float bf2f(unsigned short h) {
    return __uint_as_float(((unsigned int)h) << 16);
}
__device__ __forceinline__ float bf_lo(unsigned int u) { return __uint_as_float(u << 16); }
__device__ __forceinline__ float bf_hi(unsigned int u) { return __uint_as_float(u & 0xffff0000u); }
__device__ __forceinline__ float bfdot(unsigned int a, unsigned int b) {
    return bf_lo(a) * bf_lo(b) + bf_hi(a) * bf_hi(b);
}

__global__ void fill_i(int* __restrict__ p, int v, int n) {
    int i = blockIdx.x * blockDim.x + threadIdx.x;
    if (i < n) p[i] = v;
}

// combined histogram over [L | P | X] target-node space
__global__ __launch_bounds__(256) void hist_all_kernel(const int* __restrict__ tgtL,
        const int* __restrict__ tgtP, const int* __restrict__ ctgt, int* __restrict__ count,
        int E_L, int E_P, int E_X, int N_L, int N_P) {
    int e = blockIdx.x * blockDim.x + threadIdx.x;
    if (e < E_L) atomicAdd(&count[tgtL[e]], 1);
    else if (e < E_L + E_P) atomicAdd(&count[N_L + tgtP[e - E_L]], 1);
    else if (e < E_L + E_P + E_X) atomicAdd(&count[N_L + N_P + ctgt[e - E_L - E_P]], 1);
}

// ---- hierarchical scan ----
__global__ __launch_bounds__(256) void scan_blocksum_kernel(const int* __restrict__ count,
                                                            int* __restrict__ bsum, int n) {
    int b = blockIdx.x, t = threadIdx.x;
    int base = b * 4096 + t * 16;
    int s = 0;
#pragma unroll
    for (int k = 0; k < 16; ++k) {
        int idx = base + k;
        s += (idx < n) ? count[idx] : 0;
    }
#pragma unroll
    for (int off = 1; off < 64; off <<= 1) s += __shfl_xor(s, off, 64);
    __shared__ int ws[4];
    int lane = t & 63, wid = t >> 6;
    if (lane == 0) ws[wid] = s;
    __syncthreads();
    if (t == 0) bsum[b] = ws[0] + ws[1] + ws[2] + ws[3];
}

__global__ void scan_top_kernel(int* __restrict__ bsum, int nb, float* __restrict__ csc) {
    if (threadIdx.x == 0) {
        int run = 0;
        for (int i = 0; i < nb; ++i) { int c = bsum[i]; bsum[i] = run; run += c; }
        csc[0] = -3.4e38f; csc[1] = 0.f;
    }
}

__global__ __launch_bounds__(256) void scan_apply_kernel(const int* __restrict__ count,
        const int* __restrict__ bsum, int* __restrict__ rowptr, int* __restrict__ cursor,
        int n, int E) {
    int b = blockIdx.x, t = threadIdx.x;
    int base = b * 4096 + t * 16;
    int v[16];
    int s = 0;
#pragma unroll
    for (int k = 0; k < 16; ++k) {
        int idx = base + k;
        v[k] = (idx < n) ? count[idx] : 0;
        s += v[k];
    }
    int lane = t & 63, wid = t >> 6;
    int inc = s;
#pragma unroll
    for (int off = 1; off < 64; off <<= 1) {
        int o = __shfl_up(inc, off, 64);
        if (lane >= off) inc += o;
    }
    __shared__ int ws[4];
    if (lane == 63) ws[wid] = inc;
    __syncthreads();
    int woff = 0;
    for (int w = 0; w < wid; ++w) woff += ws[w];
    int prefix = bsum[b] + woff + (inc - s);
#pragma unroll
    for (int k = 0; k < 16; ++k) {
        int idx = base + k;
        if (idx < n) { rowptr[idx] = prefix; cursor[idx] = prefix; prefix += v[k]; }
    }
    if (b == 0 && t == 0) rowptr[n] = E;
}

// combined CSR fill, 4-byte packed payloads
__global__ __launch_bounds__(256) void pre_all_kernel(const int* __restrict__ eL,
        const int* __restrict__ eP, const int* __restrict__ csrc, const int* __restrict__ ctgt,
        const float* __restrict__ posL, const float* __restrict__ posP,
        int* __restrict__ cursor, unsigned int* __restrict__ sdp,
        int E_L, int E_P, int E_X, int N_L, int N_P) {
    int e = blockIdx.x * blockDim.x + threadIdx.x;
    if (e >= E_L + E_P + E_X) return;
    unsigned int pack;
    int node;
    if (e < E_L + E_P) {
        const int* ed; const float* pos; int idx, E, nbase;
        if (e < E_L) { ed = eL; pos = posL; idx = e; E = E_L; nbase = 0; }
        else         { ed = eP; pos = posP; idx = e - E_L; E = E_P; nbase = N_L; }
        int si = ed[idx], ti = ed[E + idx];
        node = nbase + ti;
        float dx = pos[si * 3 + 0] - pos[ti * 3 + 0];
        float dy = pos[si * 3 + 1] - pos[ti * 3 + 1];
        float dz = pos[si * 3 + 2] - pos[ti * 3 + 2];
        float dist = sqrtf(dx * dx + dy * dy + dz * dz);
        int dq = min((int)(dist * 4096.f), 65535);
        pack = (unsigned int)(si + nbase) | ((unsigned int)dq << 16);
    } else {
        int idx = e - E_L - E_P;
        int ti = ctgt[idx];
        pack = (unsigned int)csrc[idx] | ((unsigned int)ti << 16);
        node = N_L + N_P + ti;
    }
    int p = atomicAdd(&cursor[node], 1);
    sdp[p] = pack;
}

// packed RBF@We table
__global__ __launch_bounds__(96) void rbf_table_pack_kernel(const float* __restrict__ We_L,
        const float* __restrict__ We_P, unsigned int* __restrict__ T2_L,
        unsigned int* __restrict__ T2_P) {
    int b = blockIdx.x;
    const float* We = (b < 1024) ? We_L : We_P;
    unsigned int* T2 = (b < 1024) ? T2_L : T2_P;
    int i = (b < 1024) ? b : b - 1024;
    int h = threadIdx.x;
    float d0 = (float)i * 0.015625f, d1 = (float)(i + 1) * 0.015625f;
    float a0 = 0.f, a1 = 0.f;
#pragma unroll
    for (int g = 0; g < 16; ++g) {
        float w = We[g * 96 + h];
        float t0 = d0 - 0.66666667f * (float)g;
        float t1 = d1 - 0.66666667f * (float)g;
        a0 += __expf(-1.125f * t0 * t0) * w;
        a1 += __expf(-1.125f * t1 * t1) * w;
    }
    T2[i * 96 + h] = (unsigned int)f2bf(a0) | ((unsigned int)f2bf(a1 - a0) << 16);
}

// Combined L+P GATv2: half-wave per combined node; xr now bf16.
__global__ __launch_bounds__(256) void gat_all_kernel(const int* __restrict__ rowptr,
        const unsigned int* __restrict__ sdp, const unsigned short* __restrict__ xlb,
        const unsigned short* __restrict__ xrb,
        const unsigned int* __restrict__ T2_L, const unsigned int* __restrict__ T2_P,
        const float* __restrict__ att_L, const float* __restrict__ att_P,
        const float* __restrict__ bias_L, const float* __restrict__ bias_P,
        float* __restrict__ s_L, float* __restrict__ s_P, int N_L, int Ncomb) {
    int tid = threadIdx.x;
    int l = tid & 31;
    int n = blockIdx.x * 8 + (tid >> 5);
    if (n >= Ncomb) return;
    bool isL = n < N_L;
    const unsigned int* T2 = isL ? T2_L : T2_P;
    const float* att = isL ? att_L : att_P;
    const float* bias = isL ? bias_L : bias_P;
    float* srow = isL ? (s_L + (size_t)n * 96) : (s_P + (size_t)(n - N_L) * 96);
    float att0 = att[l], att1 = att[32 + l], att2 = att[64 + l];
    size_t nb = (size_t)n * 96;
    float xr0 = bf2f(xrb[nb + l]), xr1 = bf2f(xrb[nb + 32 + l]), xr2 = bf2f(xrb[nb + 64 + l]);
    int beg = rowptr[n], end = rowptr[n + 1];
    float m = -3.4e38f, d = 0.f, a0 = 0.f, a1 = 0.f, a2 = 0.f;
    for (int j = beg; j < end; j += 4) {
        unsigned int tp0[4], tp1[4], tp2[4];
        unsigned short xs0[4], xs1[4], xs2[4];
        float ff[4];
#pragma unroll
        for (int k = 0; k < 4; ++k) {
            int jj = min(j + k, end - 1);
            unsigned int u = sdp[jj];
            int src = (int)(u & 0xffffu);
            int dq = (int)(u >> 16);
            int i = dq >> 6;
            ff[k] = (float)(dq & 63) * 0.015625f;
            const unsigned int* tr = T2 + (size_t)i * 96;
            tp0[k] = tr[l]; tp1[k] = tr[32 + l]; tp2[k] = tr[64 + l];
            const unsigned short* xp = xlb + (size_t)src * 96;
            xs0[k] = xp[l]; xs1[k] = xp[32 + l]; xs2[k] = xp[64 + l];
        }
        float y0[4], y1[4], y2[4], lt[4];
#pragma unroll
        for (int k = 0; k < 4; ++k) {
            y0[k] = bf2f(xs0[k]); y1[k] = bf2f(xs1[k]); y2[k] = bf2f(xs2[k]);
            float v0 = y0[k] + xr0 + bf_lo(tp0[k]) + ff[k] * bf_hi(tp0[k]);
            float v1 = y1[k] + xr1 + bf_lo(tp1[k]) + ff[k] * bf_hi(tp1[k]);
            float v2 = y2[k] + xr2 + bf_lo(tp2[k]) + ff[k] * bf_hi(tp2[k]);
            v0 = fmaxf(v0, 0.f) + 0.2f * fminf(v0, 0.f);
            v1 = fmaxf(v1, 0.f) + 0.2f * fminf(v1, 0.f);
            v2 = fmaxf(v2, 0.f) + 0.2f * fminf(v2, 0.f);
            float t = v0 * att0 + v1 * att1 + v2 * att2;
#pragma unroll
            for (int off = 1; off < 32; off <<= 1) t += __shfl_xor(t, off, 64);
            lt[k] = (j + k < end) ? t : -3.4e38f;
        }
        float bm = fmaxf(fmaxf(lt[0], lt[1]), fmaxf(lt[2], lt[3]));
        float nm = fmaxf(m, bm);
        float sc = __expf(m - nm);
        d *= sc; a0 *= sc; a1 *= sc; a2 *= sc;
#pragma unroll
        for (int k = 0; k < 4; ++k) {
            float w = __expf(lt[k] - nm);
            d += w;
            a0 += w * y0[k]; a1 += w * y1[k]; a2 += w * y2[k];
        }
        m = nm;
    }
    float agg0 = (d > 0.f) ? a0 / d : 0.f;
    float agg1 = (d > 0.f) ? a1 / d : 0.f;
    float agg2 = (d > 0.f) ? a2 / d : 0.f;
    srow[l]      += silu_f(agg0 + bias[l]);
    srow[32 + l] += silu_f(agg1 + bias[32 + l]);
    srow[64 + l] += silu_f(agg2 + bias[64 + l]);
}

// edge-parallel cross logits
__global__ __launch_bounds__(256) void cross_logit_e_kernel(const unsigned int* __restrict__ sdX,
        const unsigned short* __restrict__ qnb, const unsigned short* __restrict__ knb,
        float* __restrict__ clog_s, float* __restrict__ csc, int E) {
    int e = blockIdx.x * blockDim.x + threadIdx.x;
    float logit = -3.4e38f;
    if (e < E) {
        unsigned int u = sdX[e];
        int src = (int)(u & 0xffffu);
        int tgt = (int)(u >> 16);
        const uint4* q4 = (const uint4*)(qnb + (size_t)tgt * 96);
        const uint4* k4 = (const uint4*)(knb + (size_t)src * 96);
        float acc = 0.f;
#pragma unroll
        for (int i = 0; i < 12; ++i) {
            uint4 qa = q4[i], ka = k4[i];
            acc += bfdot(qa.x, ka.x) + bfdot(qa.y, ka.y) + bfdot(qa.z, ka.z) + bfdot(qa.w, ka.w);
        }
        logit = acc * 0.125f;
        clog_s[e] = logit;
    }
    __shared__ float red[256];
    red[threadIdx.x] = logit; __syncthreads();
    for (int s = 128; s > 0; s >>= 1) {
        if (threadIdx.x < s) red[threadIdx.x] = fmaxf(red[threadIdx.x], red[threadIdx.x + s]);
        __syncthreads();
    }
    if (threadIdx.x == 0) atomicMaxF(&csc[0], red[0]);
}

__global__ __launch_bounds__(256) void cross_denom_kernel(const float* __restrict__ clog_s,
                                                          float* __restrict__ csc, int E) {
    int e = blockIdx.x * blockDim.x + threadIdx.x;
    float a = 0.f;
    float mg = csc[0];
    if (e < E) a = __expf(clog_s[e] - mg);
    __shared__ float red[256];
    red[threadIdx.x] = a; __syncthreads();
    for (int s = 128; s > 0; s >>= 1) {
        if (threadIdx.x < s) red[threadIdx.x] += red[threadIdx.x + s];
        __syncthreads();
    }
    if (threadIdx.x == 0) atomicAdd(&csc[1], red[0]);
}

// cross apply: half-wave per L node
__global__ __launch_bounds__(256) void cross_apply_v4_kernel(const int* __restrict__ rowptr,
        const unsigned int* __restrict__ sdp, const float* __restrict__ clog_s,
        const unsigned short* __restrict__ vnb, const float* __restrict__ csc,
        float* __restrict__ sL, int N, int baseX) {
    int tid = threadIdx.x;
    int l = tid & 31;
    int n = blockIdx.x * 8 + (tid >> 5);
    if (n >= N) return;
    int beg = rowptr[n], end = rowptr[n + 1];
    if (beg == end) return;
    float M = csc[0], invD = 1.f / csc[1];
    float a0 = 0.f, a1 = 0.f, a2 = 0.f;
    for (int j = beg; j < end; j += 4) {
        unsigned short v0[4], v1[4], v2[4]; float w[4];
#pragma unroll
        for (int k = 0; k < 4; ++k) {
            int jj = min(j + k, end - 1);
            int src = (int)(sdp[jj] & 0xffffu);
            const unsigned short* vp = vnb + (size_t)src * 96;
            v0[k] = vp[l]; v1[k] = vp[32 + l]; v2[k] = vp[64 + l];
            w[k] = (j + k < end) ? __expf(clog_s[jj - baseX] - M) : 0.f;
        }
#pragma unroll
        for (int k = 0; k < 4; ++k) {
            a0 += w[k] * bf2f(v0[k]); a1 += w[k] * bf2f(v1[k]); a2 += w[k] * bf2f(v2[k]);
        }
    }
    size_t nb = (size_t)n * 96;
    sL[nb + l]      += a0 * invD;
    sL[nb + 32 + l] += a1 * invD;
    sL[nb + 64 + l] += a2 * invD;
}

// ---------- vectorized dense kernels (4-col float4 weights, 32 rows/block) ----------

// fused embed + dual GAT-linear for L and P; thread: 4 h-cols x 4 rows.
__global__ __launch_bounds__(192) void enc_all_kernel(
        const float* __restrict__ x_L, const float* __restrict__ x_P,
        const float* __restrict__ WembL, const float* __restrict__ bembL,
        const float* __restrict__ WembP, const float* __restrict__ bembP,
        const float* __restrict__ WlL, const float* __restrict__ blL,
        const float* __restrict__ WrL, const float* __restrict__ brL,
        const float* __restrict__ WlP, const float* __restrict__ blP,
        const float* __restrict__ WrP, const float* __restrict__ brP,
        float* __restrict__ s_L, float* __restrict__ s_P,
        unsigned short* __restrict__ xlb, unsigned short* __restrict__ xrb,
        int N_L, int N_P, int D_L, int D_P, int BL) {
    __shared__ float xs[32 * 167];
    __shared__ float ss[32 * 96];
    int b = blockIdx.x;
    bool isL = b < BL;
    const float* x    = isL ? x_L : x_P;
    const float* Wemb = isL ? WembL : WembP;
    const float* bemb = isL ? bembL : bembP;
    const float* Wl   = isL ? WlL : WlP;
    const float* bl   = isL ? blL : blP;
    const float* Wr   = isL ? WrL : WrP;
    const float* br   = isL ? brL : brP;
    float* sOut = isL ? s_L : s_P;
    int N = isL ? N_L : N_P;
    int D = isL ? D_L : D_P;
    int n0 = (isL ? b : b - BL) * 32;
    int cbase = isL ? 0 : N_L;
    int t = threadIdx.x;
    int hg = t % 24, h4 = hg * 4;
    int rg = t / 24;  // 0..7, rows rg*4..rg*4+3
    for (int i = t; i < 32 * D; i += 192) {
        int r = i / D, dd = i - r * D, nn = n0 + r;
        xs[i] = (nn < N) ? x[(size_t)nn * D + dd] : 0.f;
    }
    __syncthreads();
    float4 be = *(const float4*)&bemb[h4];
    float acc[4][4];
#pragma unroll
    for (int r = 0; r < 4; ++r) { acc[r][0] = be.x; acc[r][1] = be.y; acc[r][2] = be.z; acc[r][3] = be.w; }
    const float* xrow = &xs[rg * 4 * D];
    for (int dd = 0; dd < D; ++dd) {
        float4 w = *(const float4*)&Wemb[dd * 96 + h4];
#pragma unroll
        for (int r = 0; r < 4; ++r) {
            float xv = xrow[r * D + dd];
            acc[r][0] += xv * w.x; acc[r][1] += xv * w.y;
            acc[r][2] += xv * w.z; acc[r][3] += xv * w.w;
        }
    }
#pragma unroll
    for (int r = 0; r < 4; ++r) {
        int row = rg * 4 + r, nn = n0 + row;
        float4 v = make_float4(silu_f(acc[r][0]), silu_f(acc[r][1]),
                               silu_f(acc[r][2]), silu_f(acc[r][3]));
        *(float4*)&ss[row * 96 + h4] = v;
        if (nn < N) *(float4*)&sOut[(size_t)nn * 96 + h4] = v;
    }
    __syncthreads();
    float4 b1v = *(const float4*)&bl[h4];
    float4 b2v = *(const float4*)&br[h4];
    float a1[4][4], a2[4][4];
#pragma unroll
    for (int r = 0; r < 4; ++r) {
        a1[r][0] = b1v.x; a1[r][1] = b1v.y; a1[r][2] = b1v.z; a1[r][3] = b1v.w;
        a2[r][0] = b2v.x; a2[r][1] = b2v.y; a2[r][2] = b2v.z; a2[r][3] = b2v.w;
    }
    const float* srow = &ss[rg * 4 * 96];
    for (int k = 0; k < 96; ++k) {
        float4 w1 = *(const float4*)&Wl[k * 96 + h4];
        float4 w2 = *(const float4*)&Wr[k * 96 + h4];
#pragma unroll
        for (int r = 0; r < 4; ++r) {
            float xv = srow[r * 96 + k];
            a1[r][0] += xv * w1.x; a1[r][1] += xv * w1.y; a1[r][2] += xv * w1.z; a1[r][3] += xv * w1.w;
            a2[r][0] += xv * w2.x; a2[r][1] += xv * w2.y; a2[r][2] += xv * w2.z; a2[r][3] += xv * w2.w;
        }
    }
#pragma unroll
    for (int r = 0; r < 4; ++r) {
        int nn = n0 + rg * 4 + r;
        if (nn < N) {
            size_t o = (size_t)(cbase + nn) * 96 + h4;
            *(ushort4*)&xlb[o] = make_ushort4(f2bf(a1[r][0]), f2bf(a1[r][1]), f2bf(a1[r][2]), f2bf(a1[r][3]));
            *(ushort4*)&xrb[o] = make_ushort4(f2bf(a2[r][0]), f2bf(a2[r][1]), f2bf(a2[r][2]), f2bf(a2[r][3]));
        }
    }
}

// q (L) / k,v (P) projections; 32 rows/block, 4h x 4 rows per thread.
__global__ __launch_bounds__(192) void qkv_all_kernel(
        const float* __restrict__ s_L, const float* __restrict__ s_P,
        const float* __restrict__ Wq, const float* __restrict__ bq,
        const float* __restrict__ Wk, const float* __restrict__ bk,
        const float* __restrict__ Wv, const float* __restrict__ bv,
        unsigned short* __restrict__ qnb, unsigned short* __restrict__ knb,
        unsigned short* __restrict__ vnb, int N_L, int N_P, int BL) {
    __shared__ float xs[32 * 96];
    int b = blockIdx.x;
    bool isL = b < BL;
    const float* s = isL ? s_L : s_P;
    int N = isL ? N_L : N_P;
    int n0 = (isL ? b : b - BL) * 32;
    int t = threadIdx.x;
    int hg = t % 24, h4 = hg * 4;
    int rg = t / 24;
    for (int i = t; i < 32 * 96; i += 192) {
        int r = i / 96, c = i - r * 96, nn = n0 + r;
        xs[i] = (nn < N) ? s[(size_t)nn * 96 + c] : 0.f;
    }
    __syncthreads();
    const float* srow = &xs[rg * 4 * 96];
    if (isL) {
        float4 bb = *(const float4*)&bq[h4];
        float a1[4][4];
#pragma unroll
        for (int r = 0; r < 4; ++r) { a1[r][0] = bb.x; a1[r][1] = bb.y; a1[r][2] = bb.z; a1[r][3] = bb.w; }
        for (int k = 0; k < 96; ++k) {
            float4 w = *(const float4*)&Wq[k * 96 + h4];
#pragma unroll
            for (int r = 0; r < 4; ++r) {
                float xv = srow[r * 96 + k];
                a1[r][0] += xv * w.x; a1[r][1] += xv * w.y; a1[r][2] += xv * w.z; a1[r][3] += xv * w.w;
            }
        }
#pragma unroll
        for (int r = 0; r < 4; ++r) {
            int nn = n0 + rg * 4 + r;
            if (nn < N)
                *(ushort4*)&qnb[(size_t)nn * 96 + h4] =
                    make_ushort4(f2bf(a1[r][0]), f2bf(a1[r][1]), f2bf(a1[r][2]), f2bf(a1[r][3]));
        }
    } else {
        float4 bb1 = *(const float4*)&bk[h4];
        float4 bb2 = *(const float4*)&bv[h4];
        float a1[4][4], a2[4][4];
#pragma unroll
        for (int r = 0; r < 4; ++r) {
            a1[r][0] = bb1.x; a1[r][1] = bb1.y; a1[r][2] = bb1.z; a1[r][3] = bb1.w;
            a2[r][0] = bb2.x; a2[r][1] = bb2.y; a2[r][2] = bb2.z; a2[r][3] = bb2.w;
        }
        for (int k = 0; k < 96; ++k) {
            float4 w1 = *(const float4*)&Wk[k * 96 + h4];
            float4 w2 = *(const float4*)&Wv[k * 96 + h4];
#pragma unroll
            for (int r = 0; r < 4; ++r) {
                float xv = srow[r * 96 + k];
                a1[r][0] += xv * w1.x; a1[r][1] += xv * w1.y; a1[r][2] += xv * w1.z; a1[r][3] += xv * w1.w;
                a2[r][0] += xv * w2.x; a2[r][1] += xv * w2.y; a2[r][2] += xv * w2.z; a2[r][3] += xv * w2.w;
            }
        }
#pragma unroll
        for (int r = 0; r < 4; ++r) {
            int nn = n0 + rg * 4 + r;
            if (nn < N) {
                *(ushort4*)&knb[(size_t)nn * 96 + h4] =
                    make_ushort4(f2bf(a1[r][0]), f2bf(a1[r][1]), f2bf(a1[r][2]), f2bf(a1[r][3]));
                *(ushort4*)&vnb[(size_t)nn * 96 + h4] =
                    make_ushort4(f2bf(a2[r][0]), f2bf(a2[r][1]), f2bf(a2[r][2]), f2bf(a2[r][3]));
            }
        }
    }
}

// SSM: 8 rows/block; stage1 4c x 2rows; stage2 4h x 1row.
__global__ __launch_bounds__(192) void ssm3_kernel(float* __restrict__ sL,
        const float* __restrict__ Win, const float* __restrict__ b_in,
        const float* __restrict__ Wout, const float* __restrict__ bout, int N) {
    __shared__ float row[8 * 96];
    __shared__ float u[8 * 192];
    int t = threadIdx.x;
    int n0 = blockIdx.x * 8;
    for (int i = t; i < 8 * 96; i += 192) {
        int r = i / 96, c = i - r * 96, nn = n0 + r;
        row[i] = (nn < N) ? sL[(size_t)nn * 96 + c] : 0.f;
    }
    __syncthreads();
    {
        int cg = t % 48, c4 = cg * 4;
        int rg = t / 48;  // 0..3, rows rg*2, rg*2+1
        float4 bb = *(const float4*)&b_in[c4];
        float a[2][4];
#pragma unroll
        for (int r = 0; r < 2; ++r) { a[r][0] = bb.x; a[r][1] = bb.y; a[r][2] = bb.z; a[r][3] = bb.w; }
        const float* rr = &row[rg * 2 * 96];
        for (int k = 0; k < 96; ++k) {
            float4 w = *(const float4*)&Win[k * 384 + c4];
#pragma unroll
            for (int r = 0; r < 2; ++r) {
                float xv = rr[r * 96 + k];
                a[r][0] += xv * w.x; a[r][1] += xv * w.y; a[r][2] += xv * w.z; a[r][3] += xv * w.w;
            }
        }
#pragma unroll
        for (int r = 0; r < 2; ++r) {
            int ro = rg * 2 + r;
            u[ro * 192 + c4 + 0] = silu_f(a[r][0]);
            u[ro * 192 + c4 + 1] = silu_f(a[r][1]);
            u[ro * 192 + c4 + 2] = silu_f(a[r][2]);
            u[ro * 192 + c4 + 3] = silu_f(a[r][3]);
        }
    }
    __syncthreads();
    {
        int hg = t % 24, h4 = hg * 4;
        int rg2 = t / 24;  // 0..7, one row
        float4 bb = *(const float4*)&bout[h4];
        float a[4] = {bb.x, bb.y, bb.z, bb.w};
        const float* ur = &u[rg2 * 192];
        for (int j = 0; j < 192; ++j) {
            float4 w = *(const float4*)&Wout[j * 96 + h4];
            float uv = ur[j];
            a[0] += uv * w.x; a[1] += uv * w.y; a[2] += uv * w.z; a[3] += uv * w.w;
        }
        int nn = n0 + rg2;
        if (nn < N) {
            float4 rv = *(const float4*)&row[rg2 * 96 + h4];
            *(float4*)&sL[(size_t)nn * 96 + h4] =
                make_float4(rv.x + a[0], rv.y + a[1], rv.z + a[2], rv.w + a[3]);
        }
    }
}

// head: 32 rows/block; stage1 vectorized, stage2 tiny (3 cols).
__global__ __launch_bounds__(192) void head3_kernel(const float* __restrict__ sL,
        const float* __restrict__ W1, const float* __restrict__ b1,
        const float* __restrict__ W2, const float* __restrict__ b2,
        float* __restrict__ out, int N) {
    __shared__ float buf[32 * 96];
    __shared__ float tt[32 * 96];
    int t = threadIdx.x;
    int n0 = blockIdx.x * 32;
    for (int i = t; i < 32 * 96; i += 192) {
        int r = i / 96, c = i - r * 96, nn = n0 + r;
        buf[i] = (nn < N) ? sL[(size_t)nn * 96 + c] : 0.f;
    }
    __syncthreads();
    int hg = t % 24, h4 = hg * 4;
    int rg = t / 24;
    float4 bb = *(const float4*)&b1[h4];
    float a[4][4];
#pragma unroll
    for (int r = 0; r < 4; ++r) { a[r][0] = bb.x; a[r][1] = bb.y; a[r][2] = bb.z; a[r][3] = bb.w; }
    const float* srow = &buf[rg * 4 * 96];
    for (int k = 0; k < 96; ++k) {
        float4 w = *(const float4*)&W1[k * 96 + h4];
#pragma unroll
        for (int r = 0; r < 4; ++r) {
            float xv = srow[r * 96 + k];
            a[r][0] += xv * w.x; a[r][1] += xv * w.y; a[r][2] += xv * w.z; a[r][3] += xv * w.w;
        }
    }
#pragma unroll
    for (int r = 0; r < 4; ++r) {
        int row = rg * 4 + r;
        *(float4*)&tt[row * 96 + h4] = make_float4(silu_f(a[r][0]), silu_f(a[r][1]),
                                                   silu_f(a[r][2]), silu_f(a[r][3]));
    }
    __syncthreads();
    if (t < 96) {
        int r = t / 3, c = t - r * 3;
        float o = b2[c];
        const float* tr = &tt[r * 96];
        for (int j = 0; j < 96; ++j) o += tr[j] * W2[j * 3 + c];
        int nn = n0 + r;
        if (nn < N) out[nn * 3 + c] = o;
    }
}

static inline int cdiv(int a, int b) { return (a + b - 1) / b; }

extern "C" void kernel_launch(void* const* d_in, const int* in_sizes, int n_in,
                              void* d_out, int out_size, void* d_ws, size_t ws_size,
                              hipStream_t stream) {
    const float* x_L   = (const float*)d_in[0];
    const float* pos_L = (const float*)d_in[1];
    const float* x_P   = (const float*)d_in[2];
    const float* pos_P = (const float*)d_in[3];
    const int* edge_L = (const int*)d_in[4];
    const int* edge_P = (const int*)d_in[5];
    const int* csrc   = (const int*)d_in[6];
    const int* ctgt   = (const int*)d_in[7];
    const float *Wemb_L = (const float*)d_in[8],  *bemb_L = (const float*)d_in[9];
    const float *Wl_L = (const float*)d_in[10], *bl_L = (const float*)d_in[11];
    const float *Wr_L = (const float*)d_in[12], *br_L = (const float*)d_in[13];
    const float *We_L = (const float*)d_in[14], *att_L = (const float*)d_in[15], *bias_L = (const float*)d_in[16];
    const float *Wemb_P = (const float*)d_in[17], *bemb_P = (const float*)d_in[18];
    const float *Wl_P = (const float*)d_in[19], *bl_P = (const float*)d_in[20];
    const float *Wr_P = (const float*)d_in[21], *br_P = (const float*)d_in[22];
    const float *We_P = (const float*)d_in[23], *att_P = (const float*)d_in[24], *bias_P = (const float*)d_in[25];
    const float *Win = (const float*)d_in[26], *b_in = (const float*)d_in[27];
    const float *Wout = (const float*)d_in[28], *bout = (const float*)d_in[29];
    const float *Wq = (const float*)d_in[30], *bq = (const float*)d_in[31];
    const float *Wk = (const float*)d_in[32], *bk = (const float*)d_in[33];
    const float *Wv = (const float*)d_in[34], *bv = (const float*)d_in[35];
    const float *W1 = (const float*)d_in[36], *b1 = (const float*)d_in[37];
    const float *W2 = (const float*)d_in[38], *b2 = (const float*)d_in[39];

    const int N_L = in_sizes[1] / 3;
    const int N_P = in_sizes[3] / 3;
    const int E_L = in_sizes[4] / 2;
    const int E_P = in_sizes[5] / 2;
    const int E_X = in_sizes[6];
    const int D_L = in_sizes[0] / N_L;
    const int D_P = in_sizes[2] / N_P;
    const int Ncomb = N_L + N_P;
    const int Ntot = N_L + N_P + N_L;
    const int Etot = E_L + E_P + E_X;
    const int baseX = E_L + E_P;

    // workspace layout
    float* ws = (float*)d_ws;
    float*          s_L    = ws;                                     // N_L*96 f32
    float*          s_P    = s_L + (size_t)N_L * 96;                 // N_P*96 f32
    unsigned short* xrb    = (unsigned short*)(s_P + (size_t)N_P * 96);  // Ncomb*96 bf16
    unsigned short* xlb    = xrb + (size_t)Ncomb * 96;               // Ncomb*96 bf16
    unsigned short* knb    = xlb + (size_t)Ncomb * 96;               // N_P*96 bf16
    unsigned short* vnb    = knb + (size_t)N_P * 96;                 // N_P*96 bf16
    unsigned short* qnb    = vnb + (size_t)N_P * 96;                 // N_L*96 bf16
    unsigned int*   sdp    = (unsigned int*)(qnb + (size_t)N_L * 96);// Etot u32
    float*          clog_s = (float*)(sdp + (size_t)Etot);           // E_X f32
    unsigned int*   T2_L   = (unsigned int*)(clog_s + (size_t)E_X);  // 1024*96
    unsigned int*   T2_P   = T2_L + 1024 * 96;                       // 1024*96
    int*            rowptr = (int*)(T2_P + 1024 * 96);               // Ntot+1
    int*            count  = rowptr + (size_t)Ntot + 1;              // Ntot
    int*            cursor = count + (size_t)Ntot;                   // Ntot
    float*          csc    = (float*)(cursor + (size_t)Ntot);        // 2
    int*            bsum   = (int*)(csc + 2);                        // <=16

    const int BL = cdiv(N_L, 32), BP = cdiv(N_P, 32);

    // tables + combined CSR build
    rbf_table_pack_kernel<<<2048, 96, 0, stream>>>(We_L, We_P, T2_L, T2_P);
    fill_i<<<cdiv(Ntot, 256), 256, 0, stream>>>(count, 0, Ntot);
    hist_all_kernel<<<cdiv(Etot, 256), 256, 0, stream>>>(edge_L + E_L, edge_P + E_P, ctgt,
        count, E_L, E_P, E_X, N_L, N_P);
    scan_blocksum_kernel<<<cdiv(Ntot, 4096), 256, 0, stream>>>(count, bsum, Ntot);
    scan_top_kernel<<<1, 64, 0, stream>>>(bsum, cdiv(Ntot, 4096), csc);
    scan_apply_kernel<<<cdiv(Ntot, 4096), 256, 0, stream>>>(count, bsum, rowptr, cursor, Ntot, Etot);
    pre_all_kernel<<<cdiv(Etot, 256), 256, 0, stream>>>(edge_L, edge_P, csrc, ctgt,
        pos_L, pos_P, cursor, sdp, E_L, E_P, E_X, N_L, N_P);

    // fused embed + gat-linears for both graphs
    enc_all_kernel<<<BL + BP, 192, 0, stream>>>(x_L, x_P, Wemb_L, bemb_L, Wemb_P, bemb_P,
        Wl_L, bl_L, Wr_L, br_L, Wl_P, bl_P, Wr_P, br_P,
        s_L, s_P, xlb, xrb, N_L, N_P, D_L, D_P, BL);

    // combined L+P GAT
    gat_all_kernel<<<cdiv(Ncomb, 8), 256, 0, stream>>>(rowptr, sdp, xlb, xrb, T2_L, T2_P,
        att_L, att_P, bias_L, bias_P, s_L, s_P, N_L, Ncomb);

    // SSM (L)
    ssm3_kernel<<<cdiv(N_L, 8), 192, 0, stream>>>(s_L, Win, b_in, Wout, bout, N_L);

    // cross attention
    qkv_all_kernel<<<BL + BP, 192, 0, stream>>>(s_L, s_P, Wq, bq, Wk, bk, Wv, bv,
        qnb, knb, vnb, N_L, N_P, BL);
    cross_logit_e_kernel<<<cdiv(E_X, 256), 256, 0, stream>>>(sdp + (size_t)baseX, qnb, knb,
        clog_s, csc, E_X);
    cross_denom_kernel<<<cdiv(E_X, 256), 256, 0, stream>>>(clog_s, csc, E_X);
    cross_apply_v4_kernel<<<cdiv(N_L, 8), 256, 0, stream>>>(rowptr + N_L + N_P, sdp,
        clog_s, vnb, csc, s_L, N_L, baseX);

    // head
    head3_kernel<<<cdiv(N_L, 32), 192, 0, stream>>>(s_L, W1, b1, W2, b2, (float*)d_out, N_L);
}